// Round 3
// baseline (2839.987 us; speedup 1.0000x reference)
//
#include <hip/hip_runtime.h>

#define M_TOTAL 65536   // B*T rows
#define DDIM    128     // latent dim (GEMM K)
#define KCODES  1024    // codebook size (GEMM N)
#define NQ      8       // RVQ stages
#define MROWS   64      // rows per block
#define TAU     0.25f   // margin threshold for exact-recheck (error bound ~0.01 worst-case)

typedef _Float16 half8 __attribute__((ext_vector_type(8)));
typedef _Float16 half4 __attribute__((ext_vector_type(4)));
typedef float    f32x4 __attribute__((ext_vector_type(4)));

// ---------------- shared: ||e||^2 (verified round-1 semantics) ----------------
__global__ __launch_bounds__(256) void enorm_kernel(const float* __restrict__ embed,
                                                    float* __restrict__ enorm) {
  int c = blockIdx.x * 4 + (threadIdx.x >> 6);
  int lane = threadIdx.x & 63;
  const float* e = embed + (size_t)c * DDIM;
  float v0 = e[lane];
  float v1 = e[lane + 64];
  float s = fmaf(v0, v0, v1 * v1);
  #pragma unroll
  for (int off = 32; off > 0; off >>= 1) s += __shfl_down(s, off);
  if (lane == 0) enorm[c] = s;
}

// ---------------- prep: split embed into f16x2 planes, k-chunked layout ----------------
// Ek[(s*8 + kc*2 + p)*32768 + c*32 + kl]   (kc = k>>5, kl = k&31)
__global__ __launch_bounds__(256) void esplit_kernel(const float* __restrict__ embed,
                                                     _Float16* __restrict__ Ek) {
  int g = blockIdx.x * 256 + threadIdx.x;        // 262144 float4s
  int row = g >> 5;                              // (s,c) row 0..8191
  int k4 = g & 31;
  int s = row >> 10, c = row & 1023;
  int k = k4 * 4;
  int kc = k >> 5, kl = k & 31;
  float4 v = *(const float4*)(embed + (size_t)row * DDIM + k);
  half4 h0, h1;
  float vv[4] = {v.x, v.y, v.z, v.w};
  #pragma unroll
  for (int e = 0; e < 4; ++e) {
    _Float16 a0 = (_Float16)vv[e];
    h0[e] = a0;
    h1[e] = (_Float16)(vv[e] - (float)a0);
  }
  size_t base = (size_t)(s * 8 + kc * 2) * 32768 + c * 32 + kl;
  *(half4*)(Ek + base) = h0;
  *(half4*)(Ek + base + 32768) = h1;
}

// ---------------- prep: split x into residual planes ----------------
__global__ __launch_bounds__(256) void xsplit_kernel(const float* __restrict__ x,
                                                     _Float16* __restrict__ P0,
                                                     _Float16* __restrict__ P1) {
  int g = blockIdx.x * 256 + threadIdx.x;        // 2097152 float4s
  size_t off = (size_t)g * 4;
  float4 v = *(const float4*)(x + off);
  half4 h0, h1;
  float vv[4] = {v.x, v.y, v.z, v.w};
  #pragma unroll
  for (int e = 0; e < 4; ++e) {
    _Float16 a0 = (_Float16)vv[e];
    h0[e] = a0;
    h1[e] = (_Float16)(vv[e] - (float)a0);
  }
  *(half4*)(P0 + off) = h0;
  *(half4*)(P1 + off) = h1;
}

// ---------------- main stage kernel (MFMA + margin + exact fixup) ----------------
// Block: 64 rows x all 1024 codes (8 chunks of 128). 4 waves; wave tile 64 rows x 32 codes
// (rt=0..3 row-tiles of 16, ct=0..1 code-tiles of 16). f16 16x16x32 MFMA, 3 split-terms.
// LDS (halves): As[2][64][136] @0 (17408) | Es[2][128][40] @17408 (10240) | Ens[128 f32] @27648
__global__ __launch_bounds__(256, 2) void rvq_stage_mfma(
    _Float16* __restrict__ P0, _Float16* __restrict__ P1,   // residual planes (in/out, in-place)
    const _Float16* __restrict__ Ek,
    const float* __restrict__ embed_all,    // [NQ*KCODES][DDIM] fp32
    const float* __restrict__ enorm_all,    // [NQ*KCODES]
    const float* __restrict__ x,            // original input fp32 (fixup reconstruct)
    int* __restrict__ codes,                // [NQ][M_TOTAL]
    int stage, int write_resid)
{
  extern __shared__ char smraw[];
  _Float16* sm = (_Float16*)smraw;
  float* ens = (float*)(sm + 27648);
  // overlay on Es region (bytes from smraw + 34816, 20480 B available):
  char* ov = smraw + 34816;
  float* redv1 = (float*)ov;              // 64*4
  int*   redi1 = (int*)(ov + 1024);
  float* redv2 = (float*)(ov + 2048);
  int*   bcode = (int*)(ov + 3072);       // 64
  int*   bflag = (int*)(ov + 3328);       // 64
  int*   flist = (int*)(ov + 3584);       // 64
  int*   nfp   = (int*)(ov + 3840);
  float* rowbuf= (float*)(ov + 3844);     // 128
  float* fv    = (float*)(ov + 4356);     // 256
  int*   fidx  = (int*)(ov + 5380);       // 256

  const int tid = threadIdx.x;
  const int wv = tid >> 6;
  const int l  = tid & 63;
  const int l15 = l & 15;
  const int q = l >> 4;
  const int row_base = blockIdx.x * MROWS;

  const _Float16* EkS = Ek + (size_t)stage * 262144;
  const float* embedS = embed_all + (size_t)stage * KCODES * DDIM;
  const float* enormS = enorm_all + (size_t)stage * KCODES;

  // ---- stage A planes into LDS (k-contig rows, stride 136 halves) ----
  #pragma unroll
  for (int it = 0; it < 8; ++it) {
    int ch = it * 256 + tid;
    int p = ch >> 10, rem = ch & 1023;
    int r = rem >> 4, kp = rem & 15;
    const _Float16* src = (p ? P1 : P0) + (size_t)(row_base + r) * DDIM + kp * 8;
    *(half8*)(sm + p * 8704 + r * 136 + kp * 8) = *(const half8*)src;
  }
  __syncthreads();

  // hoist A plane-0 fragments for all kchunks (A[m=lane&15][k=q*8+j])
  half8 af0[4][4];
  #pragma unroll
  for (int rt = 0; rt < 4; ++rt)
    #pragma unroll
    for (int kc = 0; kc < 4; ++kc)
      af0[rt][kc] = *(const half8*)(sm + (rt * 16 + l15) * 136 + kc * 32 + q * 8);

  float v1[16], v2[16];
  int i1[16];
  #pragma unroll
  for (int s = 0; s < 16; ++s) { v1[s] = -3.0e38f; v2[s] = -3.0e38f; i1[s] = 0x7fffffff; }

  for (int cc = 0; cc < 8; ++cc) {     // 8 chunks of 128 codes
    f32x4 acc[4][2];
    #pragma unroll
    for (int rt = 0; rt < 4; ++rt)
      #pragma unroll
      for (int ct = 0; ct < 2; ++ct) acc[rt][ct] = (f32x4){0.f, 0.f, 0.f, 0.f};

    for (int kc = 0; kc < 4; ++kc) {
      __syncthreads();
      // stage E chunk: 2 planes x 128 codes x 32 k (coalesced from k-chunked layout)
      #pragma unroll
      for (int it = 0; it < 4; ++it) {
        int ch = it * 256 + tid;
        int p = ch >> 9, rem = ch & 511;            // rem = code*4 + kp
        int code = rem >> 2, kp = rem & 3;
        const _Float16* src = EkS + (size_t)(kc * 2 + p) * 32768 + cc * 4096 + rem * 8;
        *(half8*)(sm + 17408 + p * 5120 + code * 40 + kp * 8) = *(const half8*)src;
      }
      if (kc == 0 && tid < 128) ens[tid] = enormS[cc * 128 + tid];
      __syncthreads();

      half8 af1[4], bf[2][2];
      #pragma unroll
      for (int rt = 0; rt < 4; ++rt)
        af1[rt] = *(const half8*)(sm + 8704 + (rt * 16 + l15) * 136 + kc * 32 + q * 8);
      #pragma unroll
      for (int ct = 0; ct < 2; ++ct)
        #pragma unroll
        for (int p = 0; p < 2; ++p)
          bf[ct][p] = *(const half8*)(sm + 17408 + p * 5120 + (wv * 32 + ct * 16 + l15) * 40 + q * 8);

      #pragma unroll
      for (int rt = 0; rt < 4; ++rt)
        #pragma unroll
        for (int ct = 0; ct < 2; ++ct) {
          acc[rt][ct] = __builtin_amdgcn_mfma_f32_16x16x32_f16(af0[rt][kc], bf[ct][0], acc[rt][ct], 0, 0, 0);
          acc[rt][ct] = __builtin_amdgcn_mfma_f32_16x16x32_f16(af0[rt][kc], bf[ct][1], acc[rt][ct], 0, 0, 0);
          acc[rt][ct] = __builtin_amdgcn_mfma_f32_16x16x32_f16(af1[rt],     bf[ct][0], acc[rt][ct], 0, 0, 0);
        }
    }

    // epilogue: dist = 2*dot - ||e||^2 ; running top-2 per row-slot
    #pragma unroll
    for (int ct = 0; ct < 2; ++ct) {
      float en = ens[wv * 32 + ct * 16 + l15];
      int cg = cc * 128 + wv * 32 + ct * 16 + l15;
      #pragma unroll
      for (int rt = 0; rt < 4; ++rt)
        #pragma unroll
        for (int reg = 0; reg < 4; ++reg) {
          float d = 2.0f * acc[rt][ct][reg] - en;
          int s = rt * 4 + reg;
          if (d > v1[s]) { v2[s] = v1[s]; v1[s] = d; i1[s] = cg; }
          else if (d > v2[s]) v2[s] = d;
        }
    }
  }
  __syncthreads();   // main loop done; Es region free for overlay

  // merge top-2 across the 16 lanes (l15) sharing each row
  #pragma unroll
  for (int s = 0; s < 16; ++s) {
    #pragma unroll
    for (int off = 1; off < 16; off <<= 1) {
      float ov1 = __shfl_xor(v1[s], off);
      int   oi1 = __shfl_xor(i1[s], off);
      float ov2 = __shfl_xor(v2[s], off);
      if (ov1 > v1[s] || (ov1 == v1[s] && oi1 < i1[s])) {
        float nv2 = fmaxf(v1[s], ov2);
        v1[s] = ov1; i1[s] = oi1; v2[s] = nv2;
      } else {
        v2[s] = fmaxf(v2[s], ov1);
      }
    }
  }
  if (l15 == 0) {
    #pragma unroll
    for (int s = 0; s < 16; ++s) {
      int row = (s >> 2) * 16 + q * 4 + (s & 3);
      redv1[row * 4 + wv] = v1[s];
      redi1[row * 4 + wv] = i1[s];
      redv2[row * 4 + wv] = v2[s];
    }
  }
  __syncthreads();

  if (tid < MROWS) {
    float bv1 = redv1[tid * 4], bv2 = redv2[tid * 4];
    int bi1 = redi1[tid * 4];
    #pragma unroll
    for (int w = 1; w < 4; ++w) {
      float o1 = redv1[tid * 4 + w], o2 = redv2[tid * 4 + w];
      int oi = redi1[tid * 4 + w];
      if (o1 > bv1 || (o1 == bv1 && oi < bi1)) {
        float n2 = fmaxf(bv1, o2);
        bv1 = o1; bi1 = oi; bv2 = n2;
      } else {
        bv2 = fmaxf(bv2, o1);
      }
    }
    bcode[tid] = bi1;
    bflag[tid] = (bv1 - bv2 <= TAU) ? 1 : 0;
  }
  __syncthreads();
  if (tid == 0) {
    int n = 0;
    for (int r = 0; r < MROWS; ++r) if (bflag[r]) flist[n++] = r;
    *nfp = n;
  }
  __syncthreads();
  const int nfl = *nfp;

  // ---- exact fixup for flagged rows (replicates verified round-1 fp32 semantics) ----
  for (int fi = 0; fi < nfl; ++fi) {
    int r = flist[fi];
    int gr = row_base + r;
    if (tid < DDIM) {
      float v = x[(size_t)gr * DDIM + tid];
      for (int s2 = 0; s2 < stage; ++s2) {
        int pc = codes[(size_t)s2 * M_TOTAL + gr];
        v -= embed_all[(size_t)(s2 * KCODES + pc) * DDIM + tid];
      }
      rowbuf[tid] = v;
    }
    __syncthreads();
    float bv = -3.0e38f; int bi = 0x7fffffff;
    #pragma unroll
    for (int j = 0; j < 4; ++j) {
      int c = tid * 4 + j;
      const float* e = embedS + (size_t)c * DDIM;
      float dot = 0.f;
      #pragma unroll 8
      for (int k = 0; k < DDIM; ++k) dot = fmaf(rowbuf[k], e[k], dot);
      float d = 2.0f * dot - enormS[c];
      if (d > bv) { bv = d; bi = c; }     // j ascending -> first occurrence
    }
    fv[tid] = bv; fidx[tid] = bi;
    __syncthreads();
    for (int step = 128; step > 0; step >>= 1) {
      if (tid < step) {
        float o = fv[tid + step]; int oi = fidx[tid + step];
        if (o > fv[tid] || (o == fv[tid] && oi < fidx[tid])) { fv[tid] = o; fidx[tid] = oi; }
      }
      __syncthreads();
    }
    if (tid == 0) bcode[r] = fidx[0];
    __syncthreads();
  }

  if (tid < MROWS) codes[(size_t)stage * M_TOTAL + row_base + tid] = bcode[tid];
  __syncthreads();

  // ---- residual update: rnew = (a0+a1) - e[code]; write next-stage planes ----
  if (write_resid) {
    #pragma unroll
    for (int it = 0; it < 8; ++it) {
      int idx = it * 256 + tid;
      int r = idx >> 5;
      int k4 = (idx & 31) * 4;
      int code = bcode[r];
      float4 e = *(const float4*)(embedS + (size_t)code * DDIM + k4);
      float ee[4] = {e.x, e.y, e.z, e.w};
      half4 h0, h1;
      #pragma unroll
      for (int j = 0; j < 4; ++j) {
        float a = (float)sm[r * 136 + k4 + j] + (float)sm[8704 + r * 136 + k4 + j];
        float rn = a - ee[j];
        _Float16 c0 = (_Float16)rn;
        h0[j] = c0;
        h1[j] = (_Float16)(rn - (float)c0);
      }
      size_t goff = (size_t)(row_base + r) * DDIM + k4;
      *(half4*)(P0 + goff) = h0;
      *(half4*)(P1 + goff) = h1;
    }
  }
}

// ================= fallback: round-2 verified exact-fp32 kernel =================
#define F_NCHUNK  256
#define F_KC      16
#define F_AS_STRIDE 68
#define F_ES_STRIDE 260

__global__ __launch_bounds__(256, 3) void rvq_stage_kernel(
    const float* __restrict__ rin, float* __restrict__ rout,
    const float* __restrict__ embed, const float* __restrict__ enorm,
    int* __restrict__ codes)
{
  __shared__ float smem[DDIM * F_AS_STRIDE + F_KC * F_ES_STRIDE + F_NCHUNK];
  float* As  = smem;
  float* Es  = smem + DDIM * F_AS_STRIDE;
  float* Ens = Es + F_KC * F_ES_STRIDE;
  float* red_v = Es;
  int*   red_i = (int*)(Es + 64 * 33);
  int*   bcode = (int*)(Es + 2 * 64 * 33);

  const int tid = threadIdx.x;
  const int tx = tid & 31;
  const int ty = tid >> 5;
  const int row_base = blockIdx.x * MROWS;

  #pragma unroll
  for (int it = 0; it < 8; ++it) {
    int idx = it * 256 + tid;
    int r = idx >> 5, f4 = idx & 31;
    float4 v = *(const float4*)(rin + (size_t)(row_base + r) * DDIM + f4 * 4);
    As[(4 * f4 + 0) * F_AS_STRIDE + r] = v.x;
    As[(4 * f4 + 1) * F_AS_STRIDE + r] = v.y;
    As[(4 * f4 + 2) * F_AS_STRIDE + r] = v.z;
    As[(4 * f4 + 3) * F_AS_STRIDE + r] = v.w;
  }

  float best[8]; int bidx[8];
  #pragma unroll
  for (int i = 0; i < 8; ++i) { best[i] = -3.0e38f; bidx[i] = 0x7fffffff; }

  for (int nc = 0; nc < KCODES / F_NCHUNK; ++nc) {
    float acc[8][8];
    #pragma unroll
    for (int i = 0; i < 8; ++i)
      #pragma unroll
      for (int j = 0; j < 8; ++j) acc[i][j] = 0.0f;

    for (int kc = 0; kc < DDIM / F_KC; ++kc) {
      __syncthreads();
      #pragma unroll
      for (int it = 0; it < 4; ++it) {
        int idx = it * 256 + tid;
        int c = idx >> 2, f4 = idx & 3;
        float4 v = *(const float4*)(embed + (size_t)(nc * F_NCHUNK + c) * DDIM + kc * F_KC + f4 * 4);
        Es[(4 * f4 + 0) * F_ES_STRIDE + c] = v.x;
        Es[(4 * f4 + 1) * F_ES_STRIDE + c] = v.y;
        Es[(4 * f4 + 2) * F_ES_STRIDE + c] = v.z;
        Es[(4 * f4 + 3) * F_ES_STRIDE + c] = v.w;
      }
      if (kc == 0) Ens[tid] = enorm[nc * F_NCHUNK + tid];
      __syncthreads();

      const float* pa = As + kc * F_KC * F_AS_STRIDE + ty * 8;
      const float* pe = Es + 4 * tx;
      #pragma unroll 4
      for (int k = 0; k < F_KC; ++k) {
        float4 a0 = *(const float4*)(pa + k * F_AS_STRIDE);
        float4 a1 = *(const float4*)(pa + k * F_AS_STRIDE + 4);
        float4 e0 = *(const float4*)(pe + k * F_ES_STRIDE);
        float4 e1 = *(const float4*)(pe + k * F_ES_STRIDE + 128);
        float aa[8] = {a0.x, a0.y, a0.z, a0.w, a1.x, a1.y, a1.z, a1.w};
        float ee[8] = {e0.x, e0.y, e0.z, e0.w, e1.x, e1.y, e1.z, e1.w};
        #pragma unroll
        for (int i = 0; i < 8; ++i)
          #pragma unroll
          for (int j = 0; j < 8; ++j)
            acc[i][j] = fmaf(aa[i], ee[j], acc[i][j]);
      }
    }

    #pragma unroll
    for (int j = 0; j < 8; ++j) {
      int c_local = (j < 4) ? (4 * tx + j) : (128 + 4 * tx + (j - 4));
      float en = Ens[c_local];
      int cg = nc * F_NCHUNK + c_local;
      #pragma unroll
      for (int i = 0; i < 8; ++i) {
        float dist = 2.0f * acc[i][j] - en;
        if (dist > best[i] || (dist == best[i] && cg < bidx[i])) { best[i] = dist; bidx[i] = cg; }
      }
    }
  }

  __syncthreads();
  #pragma unroll
  for (int i = 0; i < 8; ++i) {
    red_v[(ty * 8 + i) * 33 + tx] = best[i];
    red_i[(ty * 8 + i) * 33 + tx] = bidx[i];
  }
  __syncthreads();
  if (tid < MROWS) {
    float bv = red_v[tid * 33]; int bi = red_i[tid * 33];
    #pragma unroll
    for (int t = 1; t < 32; ++t) {
      float v = red_v[tid * 33 + t]; int ix = red_i[tid * 33 + t];
      if (v > bv || (v == bv && ix < bi)) { bv = v; bi = ix; }
    }
    codes[row_base + tid] = bi;
    bcode[tid] = bi;
  }
  __syncthreads();
  #pragma unroll
  for (int it = 0; it < 32; ++it) {
    int idx = it * 256 + tid;
    int r = idx >> 7, d = idx & 127;
    float e = embed[(size_t)bcode[r] * DDIM + d];
    rout[(size_t)(row_base + r) * DDIM + d] = As[d * F_AS_STRIDE + r] - e;
  }
}

extern "C" void kernel_launch(void* const* d_in, const int* in_sizes, int n_in,
                              void* d_out, int out_size, void* d_ws, size_t ws_size,
                              hipStream_t stream) {
  (void)in_sizes; (void)n_in; (void)out_size;
  const float* x = (const float*)d_in[0];
  const float* embed = (const float*)d_in[1];
  int* codes = (int*)d_out;

  const size_t P_BYTES = (size_t)M_TOTAL * DDIM * 2;              // 16 MB per plane
  const size_t EK_BYTES = (size_t)NQ * 2 * KCODES * DDIM * 2;     // 4.19 MB
  const size_t need = 2 * P_BYTES + EK_BYTES + (size_t)NQ * KCODES * 4;

  if (ws_size >= need) {
    _Float16* P0 = (_Float16*)d_ws;
    _Float16* P1 = (_Float16*)((char*)d_ws + P_BYTES);
    _Float16* Ek = (_Float16*)((char*)d_ws + 2 * P_BYTES);
    float* enorm = (float*)((char*)d_ws + 2 * P_BYTES + EK_BYTES);

    enorm_kernel<<<dim3(NQ * KCODES / 4), dim3(256), 0, stream>>>(embed, enorm);
    esplit_kernel<<<dim3(NQ * KCODES * DDIM / 4 / 256), dim3(256), 0, stream>>>(embed, Ek);
    xsplit_kernel<<<dim3((size_t)M_TOTAL * DDIM / 4 / 256), dim3(256), 0, stream>>>(x, P0, P1);

    const size_t lds = 55808;   // 27904 halves
    for (int q = 0; q < NQ; ++q) {
      rvq_stage_mfma<<<dim3(M_TOTAL / MROWS), dim3(256), lds, stream>>>(
          P0, P1, Ek, embed, enorm, x, codes, q, (q < NQ - 1) ? 1 : 0);
    }
  } else {
    // fallback: verified round-2 exact-fp32 path
    const size_t resid_elems = (size_t)M_TOTAL * DDIM;
    const bool ws_ok = ws_size >= (resid_elems + (size_t)NQ * KCODES) * sizeof(float);
    float* resid = ws_ok ? (float*)d_ws : (float*)d_in[0];
    float* enorm = ws_ok ? ((float*)d_ws + resid_elems) : (float*)d_ws;

    enorm_kernel<<<dim3(NQ * KCODES / 4), dim3(256), 0, stream>>>(embed, enorm);
    for (int q = 0; q < NQ; ++q) {
      const float* rin = (q == 0) ? x : resid;
      rvq_stage_kernel<<<dim3(M_TOTAL / MROWS), dim3(256), 0, stream>>>(
          rin, resid, embed + (size_t)q * KCODES * DDIM,
          enorm + (size_t)q * KCODES, codes + (size_t)q * M_TOTAL);
    }
  }
}

// Round 4
// 2166.280 us; speedup vs baseline: 1.3110x; 1.3110x over previous
//
#include <hip/hip_runtime.h>

#define M_TOTAL 65536   // B*T rows
#define DDIM    128     // latent dim (GEMM K)
#define KCODES  1024    // codebook size (GEMM N)
#define NQ      8       // RVQ stages
#define MROWS   64      // rows per block
#define TAU     0.25f   // margin threshold for exact-recheck (error bound ~2e-2 worst-case)
#define FB      8       // fixup rows per batch
#define FIXGRID 256

typedef _Float16 half8 __attribute__((ext_vector_type(8)));
typedef _Float16 half4 __attribute__((ext_vector_type(4)));
typedef float    f32x4 __attribute__((ext_vector_type(4)));

// ---------------- shared: ||e||^2 (verified round-1 semantics) ----------------
__global__ __launch_bounds__(256) void enorm_kernel(const float* __restrict__ embed,
                                                    float* __restrict__ enorm) {
  int c = blockIdx.x * 4 + (threadIdx.x >> 6);
  int lane = threadIdx.x & 63;
  const float* e = embed + (size_t)c * DDIM;
  float v0 = e[lane];
  float v1 = e[lane + 64];
  float s = fmaf(v0, v0, v1 * v1);
  #pragma unroll
  for (int off = 32; off > 0; off >>= 1) s += __shfl_down(s, off);
  if (lane == 0) enorm[c] = s;
}

// ---------------- prep: split embed into f16x2 planes, k-chunked layout ----------------
// Ek[(s*8 + kc*2 + p)*32768 + c*32 + kl]   (kc = k>>5, kl = k&31)
__global__ __launch_bounds__(256) void esplit_kernel(const float* __restrict__ embed,
                                                     _Float16* __restrict__ Ek) {
  int g = blockIdx.x * 256 + threadIdx.x;        // 262144 float4s
  int row = g >> 5;                              // (s,c) row 0..8191
  int k4 = g & 31;
  int s = row >> 10, c = row & 1023;
  int k = k4 * 4;
  int kc = k >> 5, kl = k & 31;
  float4 v = *(const float4*)(embed + (size_t)row * DDIM + k);
  half4 h0, h1;
  float vv[4] = {v.x, v.y, v.z, v.w};
  #pragma unroll
  for (int e = 0; e < 4; ++e) {
    _Float16 a0 = (_Float16)vv[e];
    h0[e] = a0;
    h1[e] = (_Float16)(vv[e] - (float)a0);
  }
  size_t base = (size_t)(s * 8 + kc * 2) * 32768 + c * 32 + kl;
  *(half4*)(Ek + base) = h0;
  *(half4*)(Ek + base + 32768) = h1;
}

// ---------------- prep: split x into residual planes ----------------
__global__ __launch_bounds__(256) void xsplit_kernel(const float* __restrict__ x,
                                                     _Float16* __restrict__ P0,
                                                     _Float16* __restrict__ P1) {
  int g = blockIdx.x * 256 + threadIdx.x;        // 2097152 float4s
  size_t off = (size_t)g * 4;
  float4 v = *(const float4*)(x + off);
  half4 h0, h1;
  float vv[4] = {v.x, v.y, v.z, v.w};
  #pragma unroll
  for (int e = 0; e < 4; ++e) {
    _Float16 a0 = (_Float16)vv[e];
    h0[e] = a0;
    h1[e] = (_Float16)(vv[e] - (float)a0);
  }
  *(half4*)(P0 + off) = h0;
  *(half4*)(P1 + off) = h1;
}

// ---------------- main stage kernel (MFMA + margin -> global flag list) ----------------
// Block: 64 rows x all 1024 codes (8 chunks of 128). 4 waves; wave tile 64 rows x 32 codes.
// f16 16x16x32 MFMA, 3 split-terms. Es staging software-pipelined (register prefetch).
// LDS (halves): As[2][64][136] @0 (17408h) | Es[2][128][40] @17408 (10240h) | Ens[128 f32]
__global__ __launch_bounds__(256, 2) void rvq_stage_mfma(
    const _Float16* __restrict__ P0, const _Float16* __restrict__ P1,
    _Float16* __restrict__ P0w, _Float16* __restrict__ P1w,
    const _Float16* __restrict__ Ek,
    const float* __restrict__ embed_all,    // [NQ*KCODES][DDIM] fp32
    const float* __restrict__ enorm_all,    // [NQ*KCODES]
    int* __restrict__ codes,                // [NQ][M_TOTAL]
    int* __restrict__ flist, int* __restrict__ nfp,
    int stage, int write_resid)
{
  extern __shared__ char smraw[];
  _Float16* sm = (_Float16*)smraw;
  float* ens = (float*)(sm + 27648);
  // overlay on Es region (bytes 34816.., 20480 B available):
  char* ov = smraw + 34816;
  float* redv1 = (float*)ov;              // 64*4
  int*   redi1 = (int*)(ov + 1024);
  float* redv2 = (float*)(ov + 2048);
  int*   bcode = (int*)(ov + 3072);       // 64

  const int tid = threadIdx.x;
  const int wv = tid >> 6;
  const int l  = tid & 63;
  const int l15 = l & 15;
  const int q = l >> 4;
  const int row_base = blockIdx.x * MROWS;

  const _Float16* EkS = Ek + (size_t)stage * 262144;
  const float* embedS = embed_all + (size_t)stage * KCODES * DDIM;
  const float* enormS = enorm_all + (size_t)stage * KCODES;

  // ---- stage A planes into LDS (k-contig rows, stride 136 halves) ----
  #pragma unroll
  for (int it = 0; it < 8; ++it) {
    int ch = it * 256 + tid;
    int p = ch >> 10, rem = ch & 1023;
    int r = rem >> 4, kp = rem & 15;
    const _Float16* src = (p ? P1 : P0) + (size_t)(row_base + r) * DDIM + kp * 8;
    *(half8*)(sm + p * 8704 + r * 136 + kp * 8) = *(const half8*)src;
  }
  __syncthreads();

  // hoist A plane-0 fragments for all kchunks (A[m=lane&15][k=q*8+j])
  half8 af0[4][4];
  #pragma unroll
  for (int rt = 0; rt < 4; ++rt)
    #pragma unroll
    for (int kc = 0; kc < 4; ++kc)
      af0[rt][kc] = *(const half8*)(sm + (rt * 16 + l15) * 136 + kc * 32 + q * 8);

  float v1[16], v2[16];
  int i1[16];
  #pragma unroll
  for (int s = 0; s < 16; ++s) { v1[s] = -3.0e38f; v2[s] = -3.0e38f; i1[s] = 0x7fffffff; }

  // prefetch iteration 0 (cc=0,kc=0)
  half8 pre[4];
  #pragma unroll
  for (int it = 0; it < 4; ++it) {
    int ch = it * 256 + tid;
    int p = ch >> 9, rem = ch & 511;
    pre[it] = *(const half8*)(EkS + (size_t)p * 32768 + rem * 8);
  }

  f32x4 acc[4][2];

  for (int t = 0; t < 32; ++t) {   // flat (cc,kc): cc=t>>2, kc=t&3
    const int cc = t >> 2, kc = t & 3;
    __syncthreads();
    #pragma unroll
    for (int it = 0; it < 4; ++it) {
      int ch = it * 256 + tid;
      int p = ch >> 9, rem = ch & 511;
      *(half8*)(sm + 17408 + p * 5120 + (rem >> 2) * 40 + (rem & 3) * 8) = pre[it];
    }
    if (kc == 0 && tid < 128) ens[tid] = enormS[cc * 128 + tid];
    __syncthreads();

    // prefetch next chunk while computing this one
    if (t + 1 < 32) {
      const int cc2 = (t + 1) >> 2, kc2 = (t + 1) & 3;
      #pragma unroll
      for (int it = 0; it < 4; ++it) {
        int ch = it * 256 + tid;
        int p = ch >> 9, rem = ch & 511;
        pre[it] = *(const half8*)(EkS + (size_t)(kc2 * 2 + p) * 32768 + cc2 * 4096 + rem * 8);
      }
    }

    if (kc == 0) {
      #pragma unroll
      for (int rt = 0; rt < 4; ++rt)
        #pragma unroll
        for (int ct = 0; ct < 2; ++ct) acc[rt][ct] = (f32x4){0.f, 0.f, 0.f, 0.f};
    }

    half8 af1[4], bf[2][2];
    #pragma unroll
    for (int rt = 0; rt < 4; ++rt)
      af1[rt] = *(const half8*)(sm + 8704 + (rt * 16 + l15) * 136 + kc * 32 + q * 8);
    #pragma unroll
    for (int ct = 0; ct < 2; ++ct)
      #pragma unroll
      for (int p = 0; p < 2; ++p)
        bf[ct][p] = *(const half8*)(sm + 17408 + p * 5120 + (wv * 32 + ct * 16 + l15) * 40 + q * 8);

    #pragma unroll
    for (int rt = 0; rt < 4; ++rt)
      #pragma unroll
      for (int ct = 0; ct < 2; ++ct) {
        acc[rt][ct] = __builtin_amdgcn_mfma_f32_16x16x32_f16(af0[rt][kc], bf[ct][0], acc[rt][ct], 0, 0, 0);
        acc[rt][ct] = __builtin_amdgcn_mfma_f32_16x16x32_f16(af0[rt][kc], bf[ct][1], acc[rt][ct], 0, 0, 0);
        acc[rt][ct] = __builtin_amdgcn_mfma_f32_16x16x32_f16(af1[rt],     bf[ct][0], acc[rt][ct], 0, 0, 0);
      }

    if (kc == 3) {
      // epilogue: dist = 2*dot - ||e||^2 ; running top-2 per row-slot
      #pragma unroll
      for (int ct = 0; ct < 2; ++ct) {
        float en = ens[wv * 32 + ct * 16 + l15];
        int cg = cc * 128 + wv * 32 + ct * 16 + l15;
        #pragma unroll
        for (int rt = 0; rt < 4; ++rt)
          #pragma unroll
          for (int reg = 0; reg < 4; ++reg) {
            float d = 2.0f * acc[rt][ct][reg] - en;
            int s = rt * 4 + reg;
            if (d > v1[s]) { v2[s] = v1[s]; v1[s] = d; i1[s] = cg; }
            else if (d > v2[s]) v2[s] = d;
          }
      }
    }
  }
  __syncthreads();   // main loop done; Es region free for overlay

  // merge top-2 across the 16 lanes (l15) sharing each row (disjoint code sets)
  #pragma unroll
  for (int s = 0; s < 16; ++s) {
    #pragma unroll
    for (int off = 1; off < 16; off <<= 1) {
      float ov1 = __shfl_xor(v1[s], off);
      int   oi1 = __shfl_xor(i1[s], off);
      float ov2 = __shfl_xor(v2[s], off);
      if (ov1 > v1[s] || (ov1 == v1[s] && oi1 < i1[s])) {
        float nv2 = fmaxf(v1[s], ov2);
        v1[s] = ov1; i1[s] = oi1; v2[s] = nv2;
      } else {
        v2[s] = fmaxf(v2[s], ov1);
      }
    }
  }
  if (l15 == 0) {
    #pragma unroll
    for (int s = 0; s < 16; ++s) {
      int row = (s >> 2) * 16 + q * 4 + (s & 3);
      redv1[row * 4 + wv] = v1[s];
      redi1[row * 4 + wv] = i1[s];
      redv2[row * 4 + wv] = v2[s];
    }
  }
  __syncthreads();

  if (tid < MROWS) {
    float bv1 = redv1[tid * 4], bv2 = redv2[tid * 4];
    int bi1 = redi1[tid * 4];
    #pragma unroll
    for (int w = 1; w < 4; ++w) {
      float o1 = redv1[tid * 4 + w], o2 = redv2[tid * 4 + w];
      int oi = redi1[tid * 4 + w];
      if (o1 > bv1 || (o1 == bv1 && oi < bi1)) {
        float n2 = fmaxf(bv1, o2);
        bv1 = o1; bi1 = oi; bv2 = n2;
      } else {
        bv2 = fmaxf(bv2, o1);
      }
    }
    bcode[tid] = bi1;
    codes[(size_t)stage * M_TOTAL + row_base + tid] = bi1;
    if (bv1 - bv2 <= TAU) {
      int pos = atomicAdd(nfp, 1);
      flist[pos] = row_base + tid;
    }
  }
  __syncthreads();

  // ---- residual update: rnew = (a0+a1) - e[code]; write next-stage planes ----
  if (write_resid) {
    #pragma unroll
    for (int it = 0; it < 8; ++it) {
      int idx = it * 256 + tid;
      int r = idx >> 5;
      int k4 = (idx & 31) * 4;
      int code = bcode[r];
      float4 e = *(const float4*)(embedS + (size_t)code * DDIM + k4);
      float ee[4] = {e.x, e.y, e.z, e.w};
      half4 h0, h1;
      #pragma unroll
      for (int j = 0; j < 4; ++j) {
        float a = (float)sm[r * 136 + k4 + j] + (float)sm[8704 + r * 136 + k4 + j];
        float rn = a - ee[j];
        _Float16 c0 = (_Float16)rn;
        h0[j] = c0;
        h1[j] = (_Float16)(rn - (float)c0);
      }
      size_t goff = (size_t)(row_base + r) * DDIM + k4;
      *(half4*)(P0w + goff) = h0;
      *(half4*)(P1w + goff) = h1;
    }
  }
}

// ---------------- batched exact fixup (round-1-verified fp32 semantics) ----------------
// 8 flagged rows per batch; codebook read once per batch (traffic /8 vs per-row).
__global__ __launch_bounds__(256) void rvq_fixup(
    const float* __restrict__ x,
    const float* __restrict__ embed_all, const float* __restrict__ enorm_all,
    int* __restrict__ codes, _Float16* __restrict__ P0, _Float16* __restrict__ P1,
    const int* __restrict__ flist, const int* __restrict__ nfp,
    int stage, int write_resid)
{
  __shared__ float rowbuf[FB][DDIM];
  __shared__ float fv[256];
  __shared__ int fidx[256];
  __shared__ int rowid[FB];
  __shared__ int bestc[FB];
  const int tid = threadIdx.x;
  const int n = *nfp;
  const float* embedS = embed_all + (size_t)stage * KCODES * DDIM;
  const float* enormS = enorm_all + (size_t)stage * KCODES;

  for (int base = blockIdx.x * FB; base < n; base += FIXGRID * FB) {
    const int nb = min(FB, n - base);
    if (tid < nb) rowid[tid] = flist[base + tid];
    __syncthreads();

    // reconstruct exact residual: v = x - sum_{s2<stage} embed[codes[s2]] (stage order)
    for (int j0 = 0; j0 < nb; j0 += 2) {
      int j = j0 + (tid >> 7);
      int d = tid & 127;
      if (j < nb) {
        int r = rowid[j];
        float v = x[(size_t)r * DDIM + d];
        for (int s2 = 0; s2 < stage; ++s2) {
          int pc = codes[(size_t)s2 * M_TOTAL + r];
          v -= embed_all[(size_t)(s2 * KCODES + pc) * DDIM + d];
        }
        rowbuf[j][d] = v;
      }
    }
    __syncthreads();

    // dots: thread t handles codes {4t..4t+3} x FB rows; sequential-k fmaf chains
    float acc[4][FB];
    #pragma unroll
    for (int jc = 0; jc < 4; ++jc)
      #pragma unroll
      for (int j = 0; j < FB; ++j) acc[jc][j] = 0.f;
    for (int k4 = 0; k4 < 32; ++k4) {
      float4 rb[FB];
      #pragma unroll
      for (int j = 0; j < FB; ++j) rb[j] = *(const float4*)(&rowbuf[j][k4 * 4]);
      #pragma unroll
      for (int jc = 0; jc < 4; ++jc) {
        float4 e4 = *(const float4*)(embedS + (size_t)(tid * 4 + jc) * DDIM + k4 * 4);
        #pragma unroll
        for (int j = 0; j < FB; ++j) {
          acc[jc][j] = fmaf(rb[j].x, e4.x, acc[jc][j]);
          acc[jc][j] = fmaf(rb[j].y, e4.y, acc[jc][j]);
          acc[jc][j] = fmaf(rb[j].z, e4.z, acc[jc][j]);
          acc[jc][j] = fmaf(rb[j].w, e4.w, acc[jc][j]);
        }
      }
    }

    // per-row argmax reduction (first-occurrence tie-break)
    for (int j = 0; j < nb; ++j) {
      float bv = -3.0e38f; int bi = 0x7fffffff;
      #pragma unroll
      for (int jc = 0; jc < 4; ++jc) {
        int c = tid * 4 + jc;
        float dd = 2.0f * acc[jc][j] - enormS[c];
        if (dd > bv) { bv = dd; bi = c; }   // jc ascending -> first occurrence in-thread
      }
      fv[tid] = bv; fidx[tid] = bi;
      __syncthreads();
      for (int step = 128; step > 0; step >>= 1) {
        if (tid < step) {
          float o = fv[tid + step]; int oi = fidx[tid + step];
          if (o > fv[tid] || (o == fv[tid] && oi < fidx[tid])) { fv[tid] = o; fidx[tid] = oi; }
        }
        __syncthreads();
      }
      if (tid == 0) {
        bestc[j] = fidx[0];
        codes[(size_t)stage * M_TOTAL + rowid[j]] = fidx[0];
      }
      __syncthreads();
    }

    // rewrite residual planes from the EXACT residual (resets drift on flagged rows)
    if (write_resid) {
      for (int j0 = 0; j0 < nb; j0 += 2) {
        int j = j0 + (tid >> 7);
        int d = tid & 127;
        if (j < nb) {
          int r = rowid[j];
          float rn = rowbuf[j][d] - embedS[(size_t)bestc[j] * DDIM + d];
          _Float16 c0 = (_Float16)rn;
          P0[(size_t)r * DDIM + d] = c0;
          P1[(size_t)r * DDIM + d] = (_Float16)(rn - (float)c0);
        }
      }
    }
    __syncthreads();
  }
}

// ================= fallback: round-2 verified exact-fp32 kernel =================
#define F_NCHUNK  256
#define F_KC      16
#define F_AS_STRIDE 68
#define F_ES_STRIDE 260

__global__ __launch_bounds__(256, 3) void rvq_stage_kernel(
    const float* __restrict__ rin, float* __restrict__ rout,
    const float* __restrict__ embed, const float* __restrict__ enorm,
    int* __restrict__ codes)
{
  __shared__ float smem[DDIM * F_AS_STRIDE + F_KC * F_ES_STRIDE + F_NCHUNK];
  float* As  = smem;
  float* Es  = smem + DDIM * F_AS_STRIDE;
  float* Ens = Es + F_KC * F_ES_STRIDE;
  float* red_v = Es;
  int*   red_i = (int*)(Es + 64 * 33);
  int*   bcode = (int*)(Es + 2 * 64 * 33);

  const int tid = threadIdx.x;
  const int tx = tid & 31;
  const int ty = tid >> 5;
  const int row_base = blockIdx.x * MROWS;

  #pragma unroll
  for (int it = 0; it < 8; ++it) {
    int idx = it * 256 + tid;
    int r = idx >> 5, f4 = idx & 31;
    float4 v = *(const float4*)(rin + (size_t)(row_base + r) * DDIM + f4 * 4);
    As[(4 * f4 + 0) * F_AS_STRIDE + r] = v.x;
    As[(4 * f4 + 1) * F_AS_STRIDE + r] = v.y;
    As[(4 * f4 + 2) * F_AS_STRIDE + r] = v.z;
    As[(4 * f4 + 3) * F_AS_STRIDE + r] = v.w;
  }

  float best[8]; int bidx[8];
  #pragma unroll
  for (int i = 0; i < 8; ++i) { best[i] = -3.0e38f; bidx[i] = 0x7fffffff; }

  for (int nc = 0; nc < KCODES / F_NCHUNK; ++nc) {
    float acc[8][8];
    #pragma unroll
    for (int i = 0; i < 8; ++i)
      #pragma unroll
      for (int j = 0; j < 8; ++j) acc[i][j] = 0.0f;

    for (int kc = 0; kc < DDIM / F_KC; ++kc) {
      __syncthreads();
      #pragma unroll
      for (int it = 0; it < 4; ++it) {
        int idx = it * 256 + tid;
        int c = idx >> 2, f4 = idx & 3;
        float4 v = *(const float4*)(embed + (size_t)(nc * F_NCHUNK + c) * DDIM + kc * F_KC + f4 * 4);
        Es[(4 * f4 + 0) * F_ES_STRIDE + c] = v.x;
        Es[(4 * f4 + 1) * F_ES_STRIDE + c] = v.y;
        Es[(4 * f4 + 2) * F_ES_STRIDE + c] = v.z;
        Es[(4 * f4 + 3) * F_ES_STRIDE + c] = v.w;
      }
      if (kc == 0) Ens[tid] = enorm[nc * F_NCHUNK + tid];
      __syncthreads();

      const float* pa = As + kc * F_KC * F_AS_STRIDE + ty * 8;
      const float* pe = Es + 4 * tx;
      #pragma unroll 4
      for (int k = 0; k < F_KC; ++k) {
        float4 a0 = *(const float4*)(pa + k * F_AS_STRIDE);
        float4 a1 = *(const float4*)(pa + k * F_AS_STRIDE + 4);
        float4 e0 = *(const float4*)(pe + k * F_ES_STRIDE);
        float4 e1 = *(const float4*)(pe + k * F_ES_STRIDE + 128);
        float aa[8] = {a0.x, a0.y, a0.z, a0.w, a1.x, a1.y, a1.z, a1.w};
        float ee[8] = {e0.x, e0.y, e0.z, e0.w, e1.x, e1.y, e1.z, e1.w};
        #pragma unroll
        for (int i = 0; i < 8; ++i)
          #pragma unroll
          for (int j = 0; j < 8; ++j)
            acc[i][j] = fmaf(aa[i], ee[j], acc[i][j]);
      }
    }

    #pragma unroll
    for (int j = 0; j < 8; ++j) {
      int c_local = (j < 4) ? (4 * tx + j) : (128 + 4 * tx + (j - 4));
      float en = Ens[c_local];
      int cg = nc * F_NCHUNK + c_local;
      #pragma unroll
      for (int i = 0; i < 8; ++i) {
        float dist = 2.0f * acc[i][j] - en;
        if (dist > best[i] || (dist == best[i] && cg < bidx[i])) { best[i] = dist; bidx[i] = cg; }
      }
    }
  }

  __syncthreads();
  #pragma unroll
  for (int i = 0; i < 8; ++i) {
    red_v[(ty * 8 + i) * 33 + tx] = best[i];
    red_i[(ty * 8 + i) * 33 + tx] = bidx[i];
  }
  __syncthreads();
  if (tid < MROWS) {
    float bv = red_v[tid * 33]; int bi = red_i[tid * 33];
    #pragma unroll
    for (int t = 1; t < 32; ++t) {
      float v = red_v[tid * 33 + t]; int ix = red_i[tid * 33 + t];
      if (v > bv || (v == bv && ix < bi)) { bv = v; bi = ix; }
    }
    codes[row_base + tid] = bi;
    bcode[tid] = bi;
  }
  __syncthreads();
  #pragma unroll
  for (int it = 0; it < 32; ++it) {
    int idx = it * 256 + tid;
    int r = idx >> 7, d = idx & 127;
    float e = embed[(size_t)bcode[r] * DDIM + d];
    rout[(size_t)(row_base + r) * DDIM + d] = As[d * F_AS_STRIDE + r] - e;
  }
}

extern "C" void kernel_launch(void* const* d_in, const int* in_sizes, int n_in,
                              void* d_out, int out_size, void* d_ws, size_t ws_size,
                              hipStream_t stream) {
  (void)in_sizes; (void)n_in; (void)out_size;
  const float* x = (const float*)d_in[0];
  const float* embed = (const float*)d_in[1];
  int* codes = (int*)d_out;

  const size_t P_BYTES  = (size_t)M_TOTAL * DDIM * 2;             // 16 MB per plane
  const size_t EK_BYTES = (size_t)NQ * 2 * KCODES * DDIM * 2;     // 4.19 MB
  const size_t EN_BYTES = (size_t)NQ * KCODES * 4;                // 32 KB
  const size_t FL_BYTES = (size_t)M_TOTAL * 4;                    // 256 KB
  const size_t need = 2 * P_BYTES + EK_BYTES + EN_BYTES + FL_BYTES + 64;

  if (ws_size >= need) {
    char* w = (char*)d_ws;
    _Float16* P0 = (_Float16*)w;                          w += P_BYTES;
    _Float16* P1 = (_Float16*)w;                          w += P_BYTES;
    _Float16* Ek = (_Float16*)w;                          w += EK_BYTES;
    float* enorm = (float*)w;                             w += EN_BYTES;
    int* flist   = (int*)w;                               w += FL_BYTES;
    int* nfp     = (int*)w;

    enorm_kernel<<<dim3(NQ * KCODES / 4), dim3(256), 0, stream>>>(embed, enorm);
    esplit_kernel<<<dim3(NQ * KCODES * DDIM / 4 / 256), dim3(256), 0, stream>>>(embed, Ek);
    xsplit_kernel<<<dim3((size_t)M_TOTAL * DDIM / 4 / 256), dim3(256), 0, stream>>>(x, P0, P1);

    const size_t lds = 55808;
    for (int q = 0; q < NQ; ++q) {
      int wr = (q < NQ - 1) ? 1 : 0;
      hipMemsetAsync(nfp, 0, sizeof(int), stream);
      rvq_stage_mfma<<<dim3(M_TOTAL / MROWS), dim3(256), lds, stream>>>(
          P0, P1, P0, P1, Ek, embed, enorm, codes, flist, nfp, q, wr);
      rvq_fixup<<<dim3(FIXGRID), dim3(256), 0, stream>>>(
          x, embed, enorm, codes, P0, P1, flist, nfp, q, wr);
    }
  } else {
    // fallback: verified round-2 exact-fp32 path
    const size_t resid_elems = (size_t)M_TOTAL * DDIM;
    const bool ws_ok = ws_size >= (resid_elems + (size_t)NQ * KCODES) * sizeof(float);
    float* resid = ws_ok ? (float*)d_ws : (float*)d_in[0];
    float* enorm = ws_ok ? ((float*)d_ws + resid_elems) : (float*)d_ws;

    enorm_kernel<<<dim3(NQ * KCODES / 4), dim3(256), 0, stream>>>(embed, enorm);
    for (int q = 0; q < NQ; ++q) {
      const float* rin = (q == 0) ? x : resid;
      rvq_stage_kernel<<<dim3(M_TOTAL / MROWS), dim3(256), 0, stream>>>(
          rin, resid, embed + (size_t)q * KCODES * DDIM,
          enorm + (size_t)q * KCODES, codes + (size_t)q * M_TOTAL);
    }
  }
}

// Round 5
// 1389.456 us; speedup vs baseline: 2.0440x; 1.5591x over previous
//
#include <hip/hip_runtime.h>

#define M_TOTAL 65536   // B*T rows
#define DDIM    128     // latent dim (GEMM K)
#define KCODES  1024    // codebook size (GEMM N)
#define NQ      8       // RVQ stages
#define RROWS   128     // rows per screen block
#define TAU     0.15f   // margin threshold (~16 sigma of 1-term f16 screen error)
#define FB      8       // fixup rows per batch
#define FIXGRID 256

typedef _Float16 half8 __attribute__((ext_vector_type(8)));
typedef _Float16 half4 __attribute__((ext_vector_type(4)));
typedef float    f32x4 __attribute__((ext_vector_type(4)));

// ---------------- ||e||^2 (verified round-1 semantics) ----------------
__global__ __launch_bounds__(256) void enorm_kernel(const float* __restrict__ embed,
                                                    float* __restrict__ enorm) {
  int c = blockIdx.x * 4 + (threadIdx.x >> 6);
  int lane = threadIdx.x & 63;
  const float* e = embed + (size_t)c * DDIM;
  float v0 = e[lane];
  float v1 = e[lane + 64];
  float s = fmaf(v0, v0, v1 * v1);
  #pragma unroll
  for (int off = 32; off > 0; off >>= 1) s += __shfl_down(s, off);
  if (lane == 0) enorm[c] = s;
}

// ---------------- embed -> f16 single plane, row-major ----------------
__global__ __launch_bounds__(256) void esplit16_kernel(const float* __restrict__ embed,
                                                       _Float16* __restrict__ Ef16) {
  size_t base = ((size_t)blockIdx.x * 256 + threadIdx.x) * 8;
  float4 v0 = *(const float4*)(embed + base);
  float4 v1 = *(const float4*)(embed + base + 4);
  half8 h;
  h[0] = (_Float16)v0.x; h[1] = (_Float16)v0.y; h[2] = (_Float16)v0.z; h[3] = (_Float16)v0.w;
  h[4] = (_Float16)v1.x; h[5] = (_Float16)v1.y; h[6] = (_Float16)v1.z; h[7] = (_Float16)v1.w;
  *(half8*)(Ef16 + base) = h;
}

// ---------------- screen: 1-term f16 MFMA + top-2 margin + exact f32 residual update ----
// Block: 128 rows x 1024 codes (8 chunks of 128). 4 waves in 2x2 grid:
// wave wv: rows (wv&1)*64 + rt*16, codes (wv>>1)*64 + ct*16. 16x16x32 f16 MFMA,
// A-frags (16) hoisted in registers for the whole kernel; cc-loop reads only B-frags.
__global__ __launch_bounds__(256, 2) void rvq_screen(
    const float* __restrict__ rin, float* __restrict__ rout,
    const _Float16* __restrict__ Ef16S,     // [KCODES][DDIM] f16, this stage
    const float* __restrict__ embedS,       // [KCODES][DDIM] fp32, this stage
    const float* __restrict__ enormS,       // [KCODES]
    int* __restrict__ codesS,               // [M_TOTAL] this stage
    int* __restrict__ flistS, int* __restrict__ nfpS,
    int write_resid)
{
  __shared__ _Float16 Af16[RROWS * 136];    // 34816 B, row-major, stride 136 halves
  __shared__ _Float16 Es[128 * 136];        // 34816 B, code-major, stride 136 halves
  __shared__ float ens[128];
  __shared__ float redv1[RROWS * 2];
  __shared__ float redv2[RROWS * 2];
  __shared__ int   redi1[RROWS * 2];
  __shared__ int   bcode[RROWS];

  const int tid = threadIdx.x;
  const int wv = tid >> 6;
  const int l  = tid & 63;
  const int l15 = l & 15;
  const int q = l >> 4;
  const int rw = wv & 1;         // row half (0: rows 0..63, 1: 64..127)
  const int cw = wv >> 1;        // code half within a 128-code chunk
  const int row_base = blockIdx.x * RROWS;

  // ---- stage A tile: f32 rows -> f16 LDS (16 f4 per thread) ----
  #pragma unroll
  for (int it = 0; it < 16; ++it) {
    int idx = it * 256 + tid;
    int r = idx >> 5, f4 = idx & 31;
    float4 v = *(const float4*)(rin + (size_t)(row_base + r) * DDIM + f4 * 4);
    half4 h;
    h[0] = (_Float16)v.x; h[1] = (_Float16)v.y; h[2] = (_Float16)v.z; h[3] = (_Float16)v.w;
    *(half4*)(Af16 + r * 136 + f4 * 4) = h;
  }
  __syncthreads();

  // ---- hoist A fragments: af[rt][kc], A[m=lane&15][k=q*8+j] ----
  half8 af[4][4];
  #pragma unroll
  for (int rt = 0; rt < 4; ++rt)
    #pragma unroll
    for (int kc = 0; kc < 4; ++kc)
      af[rt][kc] = *(const half8*)(Af16 + (rw * 64 + rt * 16 + l15) * 136 + kc * 32 + q * 8);

  float v1[16], v2[16];
  int i1[16];
  #pragma unroll
  for (int s = 0; s < 16; ++s) { v1[s] = -3.0e38f; v2[s] = -3.0e38f; i1[s] = 0x7fffffff; }

  for (int cc = 0; cc < 8; ++cc) {          // 8 chunks of 128 codes
    __syncthreads();                         // protect Es reuse
    #pragma unroll
    for (int it = 0; it < 8; ++it) {        // stage E chunk: 128 codes x 128 k (f16)
      int ch = it * 256 + tid;
      int code = ch >> 4, kp = ch & 15;
      half8 v = *(const half8*)(Ef16S + (size_t)(cc * 128 + code) * DDIM + kp * 8);
      *(half8*)(Es + code * 136 + kp * 8) = v;
    }
    if (tid < 128) ens[tid] = enormS[cc * 128 + tid];
    __syncthreads();

    f32x4 acc[4][4];
    #pragma unroll
    for (int rt = 0; rt < 4; ++rt)
      #pragma unroll
      for (int ct = 0; ct < 4; ++ct) acc[rt][ct] = (f32x4){0.f, 0.f, 0.f, 0.f};

    #pragma unroll
    for (int kc = 0; kc < 4; ++kc) {
      half8 bf[4];
      #pragma unroll
      for (int ct = 0; ct < 4; ++ct)
        bf[ct] = *(const half8*)(Es + (cw * 64 + ct * 16 + l15) * 136 + kc * 32 + q * 8);
      #pragma unroll
      for (int rt = 0; rt < 4; ++rt)
        #pragma unroll
        for (int ct = 0; ct < 4; ++ct)
          acc[rt][ct] = __builtin_amdgcn_mfma_f32_16x16x32_f16(af[rt][kc], bf[ct], acc[rt][ct], 0, 0, 0);
    }

    // epilogue: dist = 2*dot - ||e||^2; running top-2 per row-slot
    #pragma unroll
    for (int ct = 0; ct < 4; ++ct) {
      float en = ens[cw * 64 + ct * 16 + l15];
      int cg = cc * 128 + cw * 64 + ct * 16 + l15;
      #pragma unroll
      for (int rt = 0; rt < 4; ++rt)
        #pragma unroll
        for (int reg = 0; reg < 4; ++reg) {
          float d = 2.0f * acc[rt][ct][reg] - en;
          int s = rt * 4 + reg;
          if (d > v1[s]) { v2[s] = v1[s]; v1[s] = d; i1[s] = cg; }
          else if (d > v2[s]) v2[s] = d;
        }
    }
  }
  __syncthreads();

  // ---- merge top-2 across the 16 l15-lanes sharing each row (disjoint codes) ----
  #pragma unroll
  for (int s = 0; s < 16; ++s) {
    #pragma unroll
    for (int off = 1; off < 16; off <<= 1) {
      float ov1 = __shfl_xor(v1[s], off);
      int   oi1 = __shfl_xor(i1[s], off);
      float ov2 = __shfl_xor(v2[s], off);
      if (ov1 > v1[s] || (ov1 == v1[s] && oi1 < i1[s])) {
        float nv2 = fmaxf(v1[s], ov2);
        v1[s] = ov1; i1[s] = oi1; v2[s] = nv2;
      } else {
        v2[s] = fmaxf(v2[s], ov1);
      }
    }
  }
  if (l15 == 0) {
    #pragma unroll
    for (int s = 0; s < 16; ++s) {
      int row = rw * 64 + (s >> 2) * 16 + q * 4 + (s & 3);
      redv1[row * 2 + cw] = v1[s];
      redi1[row * 2 + cw] = i1[s];
      redv2[row * 2 + cw] = v2[s];
    }
  }
  __syncthreads();

  // ---- final per-row merge (2 code-halves), flag, code write ----
  if (tid < RROWS) {
    float a1 = redv1[tid * 2], a2 = redv2[tid * 2];
    int ai = redi1[tid * 2];
    float b1v = redv1[tid * 2 + 1], b2v = redv2[tid * 2 + 1];
    int bi = redi1[tid * 2 + 1];
    float bv1, bv2; int bidx;
    if (b1v > a1 || (b1v == a1 && bi < ai)) {
      bv1 = b1v; bidx = bi; bv2 = fmaxf(a1, b2v);
    } else {
      bv1 = a1; bidx = ai; bv2 = fmaxf(b1v, a2);
    }
    bcode[tid] = bidx;
    codesS[row_base + tid] = bidx;
    if (bv1 - bv2 <= TAU) {
      int pos = atomicAdd(nfpS, 1);
      flistS[pos] = row_base + tid;
    }
  }
  __syncthreads();

  // ---- exact f32 residual update: rout = rin - embed[code] (block owns its rows) ----
  if (write_resid) {
    #pragma unroll
    for (int it = 0; it < 16; ++it) {
      int idx = it * 256 + tid;
      int r = idx >> 5, f4 = idx & 31;
      float4 e = *(const float4*)(embedS + (size_t)bcode[r] * DDIM + f4 * 4);
      float4 v = *(const float4*)(rin + (size_t)(row_base + r) * DDIM + f4 * 4);
      float4 o;
      o.x = v.x - e.x; o.y = v.y - e.y; o.z = v.z - e.z; o.w = v.w - e.w;
      *(float4*)(rout + (size_t)(row_base + r) * DDIM + f4 * 4) = o;
    }
  }
}

// ---------------- batched exact fixup (round-1-verified fp32 semantics) ----------------
__global__ __launch_bounds__(256) void rvq_fixup(
    const float* __restrict__ x,
    const float* __restrict__ embed_all, const float* __restrict__ enorm_all,
    int* __restrict__ codes, float* __restrict__ resid,
    const int* __restrict__ flistS, const int* __restrict__ nfpS,
    int stage, int write_resid)
{
  __shared__ float rowbuf[FB][DDIM];
  __shared__ float fv[256];
  __shared__ int fidx[256];
  __shared__ int rowid[FB];
  __shared__ int bestc[FB];
  const int tid = threadIdx.x;
  const int n = *nfpS;
  const float* embedS = embed_all + (size_t)stage * KCODES * DDIM;
  const float* enormS = enorm_all + (size_t)stage * KCODES;

  for (int base = blockIdx.x * FB; base < n; base += FIXGRID * FB) {
    const int nb = min(FB, n - base);
    if (tid < nb) rowid[tid] = flistS[base + tid];
    __syncthreads();

    // reconstruct exact residual: v = x - sum_{s2<stage} embed[codes[s2]] (stage order)
    for (int j0 = 0; j0 < nb; j0 += 2) {
      int j = j0 + (tid >> 7);
      int d = tid & 127;
      if (j < nb) {
        int r = rowid[j];
        float v = x[(size_t)r * DDIM + d];
        for (int s2 = 0; s2 < stage; ++s2) {
          int pc = codes[(size_t)s2 * M_TOTAL + r];
          v -= embed_all[(size_t)(s2 * KCODES + pc) * DDIM + d];
        }
        rowbuf[j][d] = v;
      }
    }
    __syncthreads();

    // exact dots: thread t -> codes {4t..4t+3} x FB rows, sequential-k fmaf chains
    float acc[4][FB];
    #pragma unroll
    for (int jc = 0; jc < 4; ++jc)
      #pragma unroll
      for (int j = 0; j < FB; ++j) acc[jc][j] = 0.f;
    for (int k4 = 0; k4 < 32; ++k4) {
      float4 rb[FB];
      #pragma unroll
      for (int j = 0; j < FB; ++j) rb[j] = *(const float4*)(&rowbuf[j][k4 * 4]);
      #pragma unroll
      for (int jc = 0; jc < 4; ++jc) {
        float4 e4 = *(const float4*)(embedS + (size_t)(tid * 4 + jc) * DDIM + k4 * 4);
        #pragma unroll
        for (int j = 0; j < FB; ++j) {
          acc[jc][j] = fmaf(rb[j].x, e4.x, acc[jc][j]);
          acc[jc][j] = fmaf(rb[j].y, e4.y, acc[jc][j]);
          acc[jc][j] = fmaf(rb[j].z, e4.z, acc[jc][j]);
          acc[jc][j] = fmaf(rb[j].w, e4.w, acc[jc][j]);
        }
      }
    }

    for (int j = 0; j < nb; ++j) {
      float bv = -3.0e38f; int bi = 0x7fffffff;
      #pragma unroll
      for (int jc = 0; jc < 4; ++jc) {
        int c = tid * 4 + jc;
        float dd = 2.0f * acc[jc][j] - enormS[c];
        if (dd > bv) { bv = dd; bi = c; }
      }
      fv[tid] = bv; fidx[tid] = bi;
      __syncthreads();
      for (int step = 128; step > 0; step >>= 1) {
        if (tid < step) {
          float o = fv[tid + step]; int oi = fidx[tid + step];
          if (o > fv[tid] || (o == fv[tid] && oi < fidx[tid])) { fv[tid] = o; fidx[tid] = oi; }
        }
        __syncthreads();
      }
      if (tid == 0) {
        bestc[j] = fidx[0];
        codes[(size_t)stage * M_TOTAL + rowid[j]] = fidx[0];
      }
      __syncthreads();
    }

    // rewrite exact f32 residual for flagged rows
    if (write_resid) {
      for (int j0 = 0; j0 < nb; j0 += 2) {
        int j = j0 + (tid >> 7);
        int d = tid & 127;
        if (j < nb) {
          int r = rowid[j];
          resid[(size_t)r * DDIM + d] = rowbuf[j][d] - embedS[(size_t)bestc[j] * DDIM + d];
        }
      }
    }
    __syncthreads();
  }
}

// ================= fallback: round-2 verified exact-fp32 kernel =================
#define F_NCHUNK  256
#define F_KC      16
#define F_AS_STRIDE 68
#define F_ES_STRIDE 260

__global__ __launch_bounds__(256, 3) void rvq_stage_kernel(
    const float* __restrict__ rin, float* __restrict__ rout,
    const float* __restrict__ embed, const float* __restrict__ enorm,
    int* __restrict__ codes)
{
  __shared__ float smem[DDIM * F_AS_STRIDE + F_KC * F_ES_STRIDE + F_NCHUNK];
  float* As  = smem;
  float* Es  = smem + DDIM * F_AS_STRIDE;
  float* Ens = Es + F_KC * F_ES_STRIDE;
  float* red_v = Es;
  int*   red_i = (int*)(Es + 64 * 33);
  int*   bcode = (int*)(Es + 2 * 64 * 33);

  const int tid = threadIdx.x;
  const int tx = tid & 31;
  const int ty = tid >> 5;
  const int row_base = blockIdx.x * 64;

  #pragma unroll
  for (int it = 0; it < 8; ++it) {
    int idx = it * 256 + tid;
    int r = idx >> 5, f4 = idx & 31;
    float4 v = *(const float4*)(rin + (size_t)(row_base + r) * DDIM + f4 * 4);
    As[(4 * f4 + 0) * F_AS_STRIDE + r] = v.x;
    As[(4 * f4 + 1) * F_AS_STRIDE + r] = v.y;
    As[(4 * f4 + 2) * F_AS_STRIDE + r] = v.z;
    As[(4 * f4 + 3) * F_AS_STRIDE + r] = v.w;
  }

  float best[8]; int bidx[8];
  #pragma unroll
  for (int i = 0; i < 8; ++i) { best[i] = -3.0e38f; bidx[i] = 0x7fffffff; }

  for (int nc = 0; nc < KCODES / F_NCHUNK; ++nc) {
    float acc[8][8];
    #pragma unroll
    for (int i = 0; i < 8; ++i)
      #pragma unroll
      for (int j = 0; j < 8; ++j) acc[i][j] = 0.0f;

    for (int kc = 0; kc < DDIM / F_KC; ++kc) {
      __syncthreads();
      #pragma unroll
      for (int it = 0; it < 4; ++it) {
        int idx = it * 256 + tid;
        int c = idx >> 2, f4 = idx & 3;
        float4 v = *(const float4*)(embed + (size_t)(nc * F_NCHUNK + c) * DDIM + kc * F_KC + f4 * 4);
        Es[(4 * f4 + 0) * F_ES_STRIDE + c] = v.x;
        Es[(4 * f4 + 1) * F_ES_STRIDE + c] = v.y;
        Es[(4 * f4 + 2) * F_ES_STRIDE + c] = v.z;
        Es[(4 * f4 + 3) * F_ES_STRIDE + c] = v.w;
      }
      if (kc == 0) Ens[tid] = enorm[nc * F_NCHUNK + tid];
      __syncthreads();

      const float* pa = As + kc * F_KC * F_AS_STRIDE + ty * 8;
      const float* pe = Es + 4 * tx;
      #pragma unroll 4
      for (int k = 0; k < F_KC; ++k) {
        float4 a0 = *(const float4*)(pa + k * F_AS_STRIDE);
        float4 a1 = *(const float4*)(pa + k * F_AS_STRIDE + 4);
        float4 e0 = *(const float4*)(pe + k * F_ES_STRIDE);
        float4 e1 = *(const float4*)(pe + k * F_ES_STRIDE + 128);
        float aa[8] = {a0.x, a0.y, a0.z, a0.w, a1.x, a1.y, a1.z, a1.w};
        float ee[8] = {e0.x, e0.y, e0.z, e0.w, e1.x, e1.y, e1.z, e1.w};
        #pragma unroll
        for (int i = 0; i < 8; ++i)
          #pragma unroll
          for (int j = 0; j < 8; ++j)
            acc[i][j] = fmaf(aa[i], ee[j], acc[i][j]);
      }
    }

    #pragma unroll
    for (int j = 0; j < 8; ++j) {
      int c_local = (j < 4) ? (4 * tx + j) : (128 + 4 * tx + (j - 4));
      float en = Ens[c_local];
      int cg = nc * F_NCHUNK + c_local;
      #pragma unroll
      for (int i = 0; i < 8; ++i) {
        float dist = 2.0f * acc[i][j] - en;
        if (dist > best[i] || (dist == best[i] && cg < bidx[i])) { best[i] = dist; bidx[i] = cg; }
      }
    }
  }

  __syncthreads();
  #pragma unroll
  for (int i = 0; i < 8; ++i) {
    red_v[(ty * 8 + i) * 33 + tx] = best[i];
    red_i[(ty * 8 + i) * 33 + tx] = bidx[i];
  }
  __syncthreads();
  if (tid < 64) {
    float bv = red_v[tid * 33]; int bi = red_i[tid * 33];
    #pragma unroll
    for (int t = 1; t < 32; ++t) {
      float v = red_v[tid * 33 + t]; int ix = red_i[tid * 33 + t];
      if (v > bv || (v == bv && ix < bi)) { bv = v; bi = ix; }
    }
    codes[row_base + tid] = bi;
    bcode[tid] = bi;
  }
  __syncthreads();
  #pragma unroll
  for (int it = 0; it < 32; ++it) {
    int idx = it * 256 + tid;
    int r = idx >> 7, d = idx & 127;
    float e = embed[(size_t)bcode[r] * DDIM + d];
    rout[(size_t)(row_base + r) * DDIM + d] = As[d * F_AS_STRIDE + r] - e;
  }
}

extern "C" void kernel_launch(void* const* d_in, const int* in_sizes, int n_in,
                              void* d_out, int out_size, void* d_ws, size_t ws_size,
                              hipStream_t stream) {
  (void)in_sizes; (void)n_in; (void)out_size;
  const float* x = (const float*)d_in[0];
  const float* embed = (const float*)d_in[1];
  int* codes = (int*)d_out;

  const size_t R_BYTES  = (size_t)M_TOTAL * DDIM * 4;             // 32 MB f32 residual
  const size_t E16_BYTES = (size_t)NQ * KCODES * DDIM * 2;        // 2 MB f16 codebook
  const size_t EN_BYTES = (size_t)NQ * KCODES * 4;                // 32 KB
  const size_t FL_BYTES = (size_t)NQ * M_TOTAL * 4;               // 2 MB flag lists
  const size_t need = R_BYTES + E16_BYTES + EN_BYTES + FL_BYTES + 256;

  if (ws_size >= need) {
    char* w = (char*)d_ws;
    float* resid    = (float*)w;        w += R_BYTES;
    _Float16* Ef16  = (_Float16*)w;     w += E16_BYTES;
    float* enorm    = (float*)w;        w += EN_BYTES;
    int* flist      = (int*)w;          w += FL_BYTES;
    int* nfp        = (int*)w;

    hipMemsetAsync(nfp, 0, NQ * sizeof(int), stream);
    enorm_kernel<<<dim3(NQ * KCODES / 4), dim3(256), 0, stream>>>(embed, enorm);
    esplit16_kernel<<<dim3(NQ * KCODES * DDIM / 8 / 256), dim3(256), 0, stream>>>(embed, Ef16);

    for (int q = 0; q < NQ; ++q) {
      int wr = (q < NQ - 1) ? 1 : 0;
      const float* rin = (q == 0) ? x : resid;
      rvq_screen<<<dim3(M_TOTAL / RROWS), dim3(256), 0, stream>>>(
          rin, resid,
          Ef16 + (size_t)q * KCODES * DDIM,
          embed + (size_t)q * KCODES * DDIM,
          enorm + (size_t)q * KCODES,
          codes + (size_t)q * M_TOTAL,
          flist + (size_t)q * M_TOTAL, nfp + q, wr);
      rvq_fixup<<<dim3(FIXGRID), dim3(256), 0, stream>>>(
          x, embed, enorm, codes, resid,
          flist + (size_t)q * M_TOTAL, nfp + q, q, wr);
    }
  } else {
    // fallback: verified round-2 exact-fp32 path
    const size_t resid_elems = (size_t)M_TOTAL * DDIM;
    const bool ws_ok = ws_size >= (resid_elems + (size_t)NQ * KCODES) * sizeof(float);
    float* resid = ws_ok ? (float*)d_ws : (float*)d_in[0];
    float* enorm = ws_ok ? ((float*)d_ws + resid_elems) : (float*)d_ws;

    enorm_kernel<<<dim3(NQ * KCODES / 4), dim3(256), 0, stream>>>(embed, enorm);
    for (int q = 0; q < NQ; ++q) {
      const float* rin = (q == 0) ? x : resid;
      rvq_stage_kernel<<<dim3(M_TOTAL / 64), dim3(256), 0, stream>>>(
          rin, resid, embed + (size_t)q * KCODES * DDIM,
          enorm + (size_t)q * KCODES, codes + (size_t)q * M_TOTAL);
    }
  }
}

// Round 6
// 1099.373 us; speedup vs baseline: 2.5833x; 1.2639x over previous
//
#include <hip/hip_runtime.h>

#define M_TOTAL 65536   // B*T rows
#define DDIM    128     // latent dim (GEMM K)
#define KCODES  1024    // codebook size (GEMM N)
#define NQ      8       // RVQ stages
#define RROWS   64      // rows per screen block
#define NC      64      // codes per Es chunk
#define TAU     0.15f   // margin threshold (validated round 5, absmax 0)
#define FB      8       // fixup rows per batch
#define FIXGRID 256

typedef _Float16 half8 __attribute__((ext_vector_type(8)));
typedef _Float16 half4 __attribute__((ext_vector_type(4)));
typedef float    f32x4 __attribute__((ext_vector_type(4)));

// ---------------- ||e||^2 (verified round-1 semantics) ----------------
__global__ __launch_bounds__(256) void enorm_kernel(const float* __restrict__ embed,
                                                    float* __restrict__ enorm) {
  int c = blockIdx.x * 4 + (threadIdx.x >> 6);
  int lane = threadIdx.x & 63;
  const float* e = embed + (size_t)c * DDIM;
  float v0 = e[lane];
  float v1 = e[lane + 64];
  float s = fmaf(v0, v0, v1 * v1);
  #pragma unroll
  for (int off = 32; off > 0; off >>= 1) s += __shfl_down(s, off);
  if (lane == 0) enorm[c] = s;
}

// ---------------- embed -> f16 plane, row-major ----------------
__global__ __launch_bounds__(256) void esplit16_kernel(const float* __restrict__ embed,
                                                       _Float16* __restrict__ Ef16) {
  size_t base = ((size_t)blockIdx.x * 256 + threadIdx.x) * 8;
  float4 v0 = *(const float4*)(embed + base);
  float4 v1 = *(const float4*)(embed + base + 4);
  half8 h;
  h[0] = (_Float16)v0.x; h[1] = (_Float16)v0.y; h[2] = (_Float16)v0.z; h[3] = (_Float16)v0.w;
  h[4] = (_Float16)v1.x; h[5] = (_Float16)v1.y; h[6] = (_Float16)v1.z; h[7] = (_Float16)v1.w;
  *(half8*)(Ef16 + base) = h;
}

// ---------------- screen: f16 MFMA + top-2 margin + exact f32 residual from LDS ----
// Block: 64 rows x 1024 codes (16 chunks of 64). Waves 2x2: rw=wv&1 -> rows rw*32+rt*16,
// cw=wv>>1 -> codes cw*32+ct*16 within a chunk. A exact f32 in LDS; f16 A-frags built
// once; residual update reads LDS (no rin global re-read). ~110 VGPR -> no spill.
__global__ __launch_bounds__(256, 3) void rvq_screen(
    const float* __restrict__ rin, float* __restrict__ rout,
    const _Float16* __restrict__ Ef16S,     // [KCODES][DDIM] f16, this stage
    const float* __restrict__ embedS,       // [KCODES][DDIM] fp32, this stage
    const float* __restrict__ enormS,       // [KCODES]
    int* __restrict__ codesS,               // [M_TOTAL] this stage
    int* __restrict__ flistS, int* __restrict__ nfpS,
    int write_resid)
{
  __shared__ float Asf[RROWS * 132];        // 33792 B exact f32 A, stride 132 (16B-aligned, 2-way banks)
  __shared__ _Float16 Es[NC * 136];         // 17408 B f16 E chunk, stride 136 halves
  __shared__ float ens[NC];                 // 256 B
  // overlays on Es after the main loop:
  float* redv1 = (float*)Es;                // [64][2]
  float* redv2 = redv1 + 128;               // [64][2]
  int*   redi1 = (int*)(redv2 + 128);       // [64][2]
  int*   bcode = redi1 + 128;               // [64]

  const int tid = threadIdx.x;
  const int wv = tid >> 6;
  const int l  = tid & 63;
  const int l15 = l & 15;
  const int q = l >> 4;
  const int rw = wv & 1;
  const int cw = wv >> 1;
  const int row_base = blockIdx.x * RROWS;

  // ---- stage A tile exact f32 ----
  #pragma unroll
  for (int it = 0; it < 8; ++it) {
    int idx = it * 256 + tid;
    int r = idx >> 5, f4 = idx & 31;
    float4 v = *(const float4*)(rin + (size_t)(row_base + r) * DDIM + f4 * 4);
    *(float4*)(Asf + r * 132 + f4 * 4) = v;
  }
  __syncthreads();

  // ---- build f16 A-frags once: af[rt][kc], A[m=lane&15][k=q*8+j] ----
  half8 af[2][4];
  #pragma unroll
  for (int rt = 0; rt < 2; ++rt)
    #pragma unroll
    for (int kc = 0; kc < 4; ++kc) {
      const float* p = Asf + (rw * 32 + rt * 16 + l15) * 132 + kc * 32 + q * 8;
      float4 x0 = *(const float4*)p;
      float4 x1 = *(const float4*)(p + 4);
      half8 h;
      h[0] = (_Float16)x0.x; h[1] = (_Float16)x0.y; h[2] = (_Float16)x0.z; h[3] = (_Float16)x0.w;
      h[4] = (_Float16)x1.x; h[5] = (_Float16)x1.y; h[6] = (_Float16)x1.z; h[7] = (_Float16)x1.w;
      af[rt][kc] = h;
    }

  float v1[8], v2[8];
  int i1[8];
  #pragma unroll
  for (int s = 0; s < 8; ++s) { v1[s] = -3.0e38f; v2[s] = -3.0e38f; i1[s] = 0x7fffffff; }

  for (int cc = 0; cc < KCODES / NC; ++cc) {     // 16 chunks of 64 codes
    __syncthreads();
    #pragma unroll
    for (int it = 0; it < 4; ++it) {             // stage E chunk (64 codes x 128 k)
      int ch = it * 256 + tid;
      int code = ch >> 4, kp = ch & 15;
      *(half8*)(Es + code * 136 + kp * 8) =
          *(const half8*)(Ef16S + (size_t)(cc * NC + code) * DDIM + kp * 8);
    }
    if (tid < NC) ens[tid] = enormS[cc * NC + tid];
    __syncthreads();

    f32x4 acc[2][2];
    #pragma unroll
    for (int rt = 0; rt < 2; ++rt)
      #pragma unroll
      for (int ct = 0; ct < 2; ++ct) acc[rt][ct] = (f32x4){0.f, 0.f, 0.f, 0.f};

    #pragma unroll
    for (int kc = 0; kc < 4; ++kc) {
      half8 bf0 = *(const half8*)(Es + (cw * 32 + l15) * 136 + kc * 32 + q * 8);
      half8 bf1 = *(const half8*)(Es + (cw * 32 + 16 + l15) * 136 + kc * 32 + q * 8);
      #pragma unroll
      for (int rt = 0; rt < 2; ++rt) {
        acc[rt][0] = __builtin_amdgcn_mfma_f32_16x16x32_f16(af[rt][kc], bf0, acc[rt][0], 0, 0, 0);
        acc[rt][1] = __builtin_amdgcn_mfma_f32_16x16x32_f16(af[rt][kc], bf1, acc[rt][1], 0, 0, 0);
      }
    }

    // epilogue: dist = 2*dot - ||e||^2; running top-2 per row-slot
    #pragma unroll
    for (int ct = 0; ct < 2; ++ct) {
      float en = ens[cw * 32 + ct * 16 + l15];
      int cg = cc * NC + cw * 32 + ct * 16 + l15;
      #pragma unroll
      for (int rt = 0; rt < 2; ++rt)
        #pragma unroll
        for (int reg = 0; reg < 4; ++reg) {
          float d = 2.0f * acc[rt][ct][reg] - en;
          int s = rt * 4 + reg;
          if (d > v1[s]) { v2[s] = v1[s]; v1[s] = d; i1[s] = cg; }
          else if (d > v2[s]) v2[s] = d;
        }
    }
  }
  __syncthreads();   // main loop done; Es free for overlays

  // ---- merge top-2 across 16 l15-lanes sharing each row (disjoint codes) ----
  #pragma unroll
  for (int s = 0; s < 8; ++s) {
    #pragma unroll
    for (int off = 1; off < 16; off <<= 1) {
      float ov1 = __shfl_xor(v1[s], off);
      int   oi1 = __shfl_xor(i1[s], off);
      float ov2 = __shfl_xor(v2[s], off);
      if (ov1 > v1[s] || (ov1 == v1[s] && oi1 < i1[s])) {
        float nv2 = fmaxf(v1[s], ov2);
        v1[s] = ov1; i1[s] = oi1; v2[s] = nv2;
      } else {
        v2[s] = fmaxf(v2[s], ov1);
      }
    }
  }
  if (l15 == 0) {
    #pragma unroll
    for (int s = 0; s < 8; ++s) {
      int row = rw * 32 + (s >> 2) * 16 + q * 4 + (s & 3);
      redv1[row * 2 + cw] = v1[s];
      redi1[row * 2 + cw] = i1[s];
      redv2[row * 2 + cw] = v2[s];
    }
  }
  __syncthreads();

  // ---- final per-row merge (2 code-groups), flag, code write ----
  if (tid < RROWS) {
    float a1 = redv1[tid * 2], a2 = redv2[tid * 2];
    int ai = redi1[tid * 2];
    float b1v = redv1[tid * 2 + 1], b2v = redv2[tid * 2 + 1];
    int bi = redi1[tid * 2 + 1];
    float bv1, bv2; int bidx;
    if (b1v > a1 || (b1v == a1 && bi < ai)) {
      bv1 = b1v; bidx = bi; bv2 = fmaxf(a1, b2v);
    } else {
      bv1 = a1; bidx = ai; bv2 = fmaxf(b1v, a2);
    }
    bcode[tid] = bidx;
    codesS[row_base + tid] = bidx;
    if (bv1 - bv2 <= TAU) {
      int pos = atomicAdd(nfpS, 1);
      flistS[pos] = row_base + tid;
    }
  }
  __syncthreads();

  // ---- exact f32 residual update from LDS: rout = Asf - embed[code] ----
  if (write_resid) {
    #pragma unroll
    for (int it = 0; it < 8; ++it) {
      int idx = it * 256 + tid;
      int r = idx >> 5, f4 = idx & 31;
      float4 e = *(const float4*)(embedS + (size_t)bcode[r] * DDIM + f4 * 4);
      float4 a = *(const float4*)(Asf + r * 132 + f4 * 4);
      float4 o;
      o.x = a.x - e.x; o.y = a.y - e.y; o.z = a.z - e.z; o.w = a.w - e.w;
      *(float4*)(rout + (size_t)(row_base + r) * DDIM + f4 * 4) = o;
    }
  }
}

// ---------------- batched exact fixup (round-1-verified fp32 semantics) ----------------
__global__ __launch_bounds__(256) void rvq_fixup(
    const float* __restrict__ x,
    const float* __restrict__ embed_all, const float* __restrict__ enorm_all,
    int* __restrict__ codes, float* __restrict__ resid,
    const int* __restrict__ flistS, const int* __restrict__ nfpS,
    int stage, int write_resid)
{
  __shared__ float rowbuf[FB][DDIM];
  __shared__ float fv[256];
  __shared__ int fidx[256];
  __shared__ int rowid[FB];
  __shared__ int bestc[FB];
  const int tid = threadIdx.x;
  const int n = *nfpS;
  const float* embedS = embed_all + (size_t)stage * KCODES * DDIM;
  const float* enormS = enorm_all + (size_t)stage * KCODES;

  for (int base = blockIdx.x * FB; base < n; base += FIXGRID * FB) {
    const int nb = min(FB, n - base);
    if (tid < nb) rowid[tid] = flistS[base + tid];
    __syncthreads();

    // reconstruct exact residual: v = x - sum_{s2<stage} embed[codes[s2]] (stage order)
    for (int j0 = 0; j0 < nb; j0 += 2) {
      int j = j0 + (tid >> 7);
      int d = tid & 127;
      if (j < nb) {
        int r = rowid[j];
        float v = x[(size_t)r * DDIM + d];
        for (int s2 = 0; s2 < stage; ++s2) {
          int pc = codes[(size_t)s2 * M_TOTAL + r];
          v -= embed_all[(size_t)(s2 * KCODES + pc) * DDIM + d];
        }
        rowbuf[j][d] = v;
      }
    }
    __syncthreads();

    // exact dots: thread t -> codes {4t..4t+3} x FB rows, sequential-k fmaf chains
    float acc[4][FB];
    #pragma unroll
    for (int jc = 0; jc < 4; ++jc)
      #pragma unroll
      for (int j = 0; j < FB; ++j) acc[jc][j] = 0.f;
    for (int k4 = 0; k4 < 32; ++k4) {
      float4 rb[FB];
      #pragma unroll
      for (int j = 0; j < FB; ++j) rb[j] = *(const float4*)(&rowbuf[j][k4 * 4]);
      #pragma unroll
      for (int jc = 0; jc < 4; ++jc) {
        float4 e4 = *(const float4*)(embedS + (size_t)(tid * 4 + jc) * DDIM + k4 * 4);
        #pragma unroll
        for (int j = 0; j < FB; ++j) {
          acc[jc][j] = fmaf(rb[j].x, e4.x, acc[jc][j]);
          acc[jc][j] = fmaf(rb[j].y, e4.y, acc[jc][j]);
          acc[jc][j] = fmaf(rb[j].z, e4.z, acc[jc][j]);
          acc[jc][j] = fmaf(rb[j].w, e4.w, acc[jc][j]);
        }
      }
    }

    for (int j = 0; j < nb; ++j) {
      float bv = -3.0e38f; int bi = 0x7fffffff;
      #pragma unroll
      for (int jc = 0; jc < 4; ++jc) {
        int c = tid * 4 + jc;
        float dd = 2.0f * acc[jc][j] - enormS[c];
        if (dd > bv) { bv = dd; bi = c; }
      }
      fv[tid] = bv; fidx[tid] = bi;
      __syncthreads();
      for (int step = 128; step > 0; step >>= 1) {
        if (tid < step) {
          float o = fv[tid + step]; int oi = fidx[tid + step];
          if (o > fv[tid] || (o == fv[tid] && oi < fidx[tid])) { fv[tid] = o; fidx[tid] = oi; }
        }
        __syncthreads();
      }
      if (tid == 0) {
        bestc[j] = fidx[0];
        codes[(size_t)stage * M_TOTAL + rowid[j]] = fidx[0];
      }
      __syncthreads();
    }

    // rewrite exact f32 residual for flagged rows
    if (write_resid) {
      for (int j0 = 0; j0 < nb; j0 += 2) {
        int j = j0 + (tid >> 7);
        int d = tid & 127;
        if (j < nb) {
          int r = rowid[j];
          resid[(size_t)r * DDIM + d] = rowbuf[j][d] - embedS[(size_t)bestc[j] * DDIM + d];
        }
      }
    }
    __syncthreads();
  }
}

// ================= fallback: round-2 verified exact-fp32 kernel =================
#define F_NCHUNK  256
#define F_KC      16
#define F_AS_STRIDE 68
#define F_ES_STRIDE 260

__global__ __launch_bounds__(256, 3) void rvq_stage_kernel(
    const float* __restrict__ rin, float* __restrict__ rout,
    const float* __restrict__ embed, const float* __restrict__ enorm,
    int* __restrict__ codes)
{
  __shared__ float smem[DDIM * F_AS_STRIDE + F_KC * F_ES_STRIDE + F_NCHUNK];
  float* As  = smem;
  float* Es  = smem + DDIM * F_AS_STRIDE;
  float* Ens = Es + F_KC * F_ES_STRIDE;
  float* red_v = Es;
  int*   red_i = (int*)(Es + 64 * 33);
  int*   bcode = (int*)(Es + 2 * 64 * 33);

  const int tid = threadIdx.x;
  const int tx = tid & 31;
  const int ty = tid >> 5;
  const int row_base = blockIdx.x * 64;

  #pragma unroll
  for (int it = 0; it < 8; ++it) {
    int idx = it * 256 + tid;
    int r = idx >> 5, f4 = idx & 31;
    float4 v = *(const float4*)(rin + (size_t)(row_base + r) * DDIM + f4 * 4);
    As[(4 * f4 + 0) * F_AS_STRIDE + r] = v.x;
    As[(4 * f4 + 1) * F_AS_STRIDE + r] = v.y;
    As[(4 * f4 + 2) * F_AS_STRIDE + r] = v.z;
    As[(4 * f4 + 3) * F_AS_STRIDE + r] = v.w;
  }

  float best[8]; int bidx[8];
  #pragma unroll
  for (int i = 0; i < 8; ++i) { best[i] = -3.0e38f; bidx[i] = 0x7fffffff; }

  for (int nc = 0; nc < KCODES / F_NCHUNK; ++nc) {
    float acc[8][8];
    #pragma unroll
    for (int i = 0; i < 8; ++i)
      #pragma unroll
      for (int j = 0; j < 8; ++j) acc[i][j] = 0.0f;

    for (int kc = 0; kc < DDIM / F_KC; ++kc) {
      __syncthreads();
      #pragma unroll
      for (int it = 0; it < 4; ++it) {
        int idx = it * 256 + tid;
        int c = idx >> 2, f4 = idx & 3;
        float4 v = *(const float4*)(embed + (size_t)(nc * F_NCHUNK + c) * DDIM + kc * F_KC + f4 * 4);
        Es[(4 * f4 + 0) * F_ES_STRIDE + c] = v.x;
        Es[(4 * f4 + 1) * F_ES_STRIDE + c] = v.y;
        Es[(4 * f4 + 2) * F_ES_STRIDE + c] = v.z;
        Es[(4 * f4 + 3) * F_ES_STRIDE + c] = v.w;
      }
      if (kc == 0) Ens[tid] = enorm[nc * F_NCHUNK + tid];
      __syncthreads();

      const float* pa = As + kc * F_KC * F_AS_STRIDE + ty * 8;
      const float* pe = Es + 4 * tx;
      #pragma unroll 4
      for (int k = 0; k < F_KC; ++k) {
        float4 a0 = *(const float4*)(pa + k * F_AS_STRIDE);
        float4 a1 = *(const float4*)(pa + k * F_AS_STRIDE + 4);
        float4 e0 = *(const float4*)(pe + k * F_ES_STRIDE);
        float4 e1 = *(const float4*)(pe + k * F_ES_STRIDE + 128);
        float aa[8] = {a0.x, a0.y, a0.z, a0.w, a1.x, a1.y, a1.z, a1.w};
        float ee[8] = {e0.x, e0.y, e0.z, e0.w, e1.x, e1.y, e1.z, e1.w};
        #pragma unroll
        for (int i = 0; i < 8; ++i)
          #pragma unroll
          for (int j = 0; j < 8; ++j)
            acc[i][j] = fmaf(aa[i], ee[j], acc[i][j]);
      }
    }

    #pragma unroll
    for (int j = 0; j < 8; ++j) {
      int c_local = (j < 4) ? (4 * tx + j) : (128 + 4 * tx + (j - 4));
      float en = Ens[c_local];
      int cg = nc * F_NCHUNK + c_local;
      #pragma unroll
      for (int i = 0; i < 8; ++i) {
        float dist = 2.0f * acc[i][j] - en;
        if (dist > best[i] || (dist == best[i] && cg < bidx[i])) { best[i] = dist; bidx[i] = cg; }
      }
    }
  }

  __syncthreads();
  #pragma unroll
  for (int i = 0; i < 8; ++i) {
    red_v[(ty * 8 + i) * 33 + tx] = best[i];
    red_i[(ty * 8 + i) * 33 + tx] = bidx[i];
  }
  __syncthreads();
  if (tid < 64) {
    float bv = red_v[tid * 33]; int bi = red_i[tid * 33];
    #pragma unroll
    for (int t = 1; t < 32; ++t) {
      float v = red_v[tid * 33 + t]; int ix = red_i[tid * 33 + t];
      if (v > bv || (v == bv && ix < bi)) { bv = v; bi = ix; }
    }
    codes[row_base + tid] = bi;
    bcode[tid] = bi;
  }
  __syncthreads();
  #pragma unroll
  for (int it = 0; it < 32; ++it) {
    int idx = it * 256 + tid;
    int r = idx >> 7, d = idx & 127;
    float e = embed[(size_t)bcode[r] * DDIM + d];
    rout[(size_t)(row_base + r) * DDIM + d] = As[d * F_AS_STRIDE + r] - e;
  }
}

extern "C" void kernel_launch(void* const* d_in, const int* in_sizes, int n_in,
                              void* d_out, int out_size, void* d_ws, size_t ws_size,
                              hipStream_t stream) {
  (void)in_sizes; (void)n_in; (void)out_size;
  const float* x = (const float*)d_in[0];
  const float* embed = (const float*)d_in[1];
  int* codes = (int*)d_out;

  const size_t R_BYTES   = (size_t)M_TOTAL * DDIM * 4;            // 32 MB f32 residual
  const size_t E16_BYTES = (size_t)NQ * KCODES * DDIM * 2;        // 2 MB f16 codebook
  const size_t EN_BYTES  = (size_t)NQ * KCODES * 4;               // 32 KB
  const size_t FL_BYTES  = (size_t)NQ * M_TOTAL * 4;              // 2 MB flag lists
  const size_t need = R_BYTES + E16_BYTES + EN_BYTES + FL_BYTES + 256;

  if (ws_size >= need) {
    char* w = (char*)d_ws;
    float* resid    = (float*)w;        w += R_BYTES;
    _Float16* Ef16  = (_Float16*)w;     w += E16_BYTES;
    float* enorm    = (float*)w;        w += EN_BYTES;
    int* flist      = (int*)w;          w += FL_BYTES;
    int* nfp        = (int*)w;

    hipMemsetAsync(nfp, 0, NQ * sizeof(int), stream);
    enorm_kernel<<<dim3(NQ * KCODES / 4), dim3(256), 0, stream>>>(embed, enorm);
    esplit16_kernel<<<dim3(NQ * KCODES * DDIM / 8 / 256), dim3(256), 0, stream>>>(embed, Ef16);

    for (int q = 0; q < NQ; ++q) {
      int wr = (q < NQ - 1) ? 1 : 0;
      const float* rin = (q == 0) ? x : resid;
      rvq_screen<<<dim3(M_TOTAL / RROWS), dim3(256), 0, stream>>>(
          rin, resid,
          Ef16 + (size_t)q * KCODES * DDIM,
          embed + (size_t)q * KCODES * DDIM,
          enorm + (size_t)q * KCODES,
          codes + (size_t)q * M_TOTAL,
          flist + (size_t)q * M_TOTAL, nfp + q, wr);
      rvq_fixup<<<dim3(FIXGRID), dim3(256), 0, stream>>>(
          x, embed, enorm, codes, resid,
          flist + (size_t)q * M_TOTAL, nfp + q, q, wr);
    }
  } else {
    // fallback: verified round-2 exact-fp32 path
    const size_t resid_elems = (size_t)M_TOTAL * DDIM;
    const bool ws_ok = ws_size >= (resid_elems + (size_t)NQ * KCODES) * sizeof(float);
    float* resid = ws_ok ? (float*)d_ws : (float*)d_in[0];
    float* enorm = ws_ok ? ((float*)d_ws + resid_elems) : (float*)d_ws;

    enorm_kernel<<<dim3(NQ * KCODES / 4), dim3(256), 0, stream>>>(embed, enorm);
    for (int q = 0; q < NQ; ++q) {
      const float* rin = (q == 0) ? x : resid;
      rvq_stage_kernel<<<dim3(M_TOTAL / 64), dim3(256), 0, stream>>>(
          rin, resid, embed + (size_t)q * KCODES * DDIM,
          enorm + (size_t)q * KCODES, codes + (size_t)q * M_TOTAL);
    }
  }
}

// Round 7
// 746.099 us; speedup vs baseline: 3.8064x; 1.4735x over previous
//
#include <hip/hip_runtime.h>

#define M_TOTAL 65536   // B*T rows
#define DDIM    128     // latent dim (GEMM K)
#define KCODES  1024    // codebook size (GEMM N)
#define NQ      8       // RVQ stages
#define RROWS   128     // rows per screen block
#define NC      64      // codes per Es chunk
#define NCHUNKS (KCODES / NC)
#define TAU     0.15f   // margin threshold (validated rounds 5/6, absmax 0)
#define FB      8       // fixup rows per batch
#define FIXGRID 256

typedef _Float16 half8 __attribute__((ext_vector_type(8)));
typedef float    f32x4 __attribute__((ext_vector_type(4)));

// ---------------- ||e||^2 (verified round-1 semantics) ----------------
__global__ __launch_bounds__(256) void enorm_kernel(const float* __restrict__ embed,
                                                    float* __restrict__ enorm) {
  int c = blockIdx.x * 4 + (threadIdx.x >> 6);
  int lane = threadIdx.x & 63;
  const float* e = embed + (size_t)c * DDIM;
  float v0 = e[lane];
  float v1 = e[lane + 64];
  float s = fmaf(v0, v0, v1 * v1);
  #pragma unroll
  for (int off = 32; off > 0; off >>= 1) s += __shfl_down(s, off);
  if (lane == 0) enorm[c] = s;
}

// ---------------- embed -> f16 plane, row-major ----------------
__global__ __launch_bounds__(256) void esplit16_kernel(const float* __restrict__ embed,
                                                       _Float16* __restrict__ Ef16) {
  size_t base = ((size_t)blockIdx.x * 256 + threadIdx.x) * 8;
  float4 v0 = *(const float4*)(embed + base);
  float4 v1 = *(const float4*)(embed + base + 4);
  half8 h;
  h[0] = (_Float16)v0.x; h[1] = (_Float16)v0.y; h[2] = (_Float16)v0.z; h[3] = (_Float16)v0.w;
  h[4] = (_Float16)v1.x; h[5] = (_Float16)v1.y; h[6] = (_Float16)v1.z; h[7] = (_Float16)v1.w;
  *(half8*)(Ef16 + base) = h;
}

// ---------------- screen: f16 MFMA, double-buffered Es, top-2 margin ----------------
// Block: 128 rows x 1024 codes (16 chunks of 64). 4 waves; wave wv owns rows
// wv*32 + rt*16 + (m=l15), ALL 64 chunk codes (ct*16 + n=l15). Per-row top-2 is
// complete within one 16-lane (l15) group -> no cross-wave reduction.
// Es double-buffered: 1 barrier/chunk, global->reg prefetch overlaps compute.
__global__ __launch_bounds__(256, 2) void rvq_screen(
    const float* __restrict__ rin, float* __restrict__ rout,
    const _Float16* __restrict__ Ef16S,     // [KCODES][DDIM] f16, this stage
    const float* __restrict__ embedS,       // [KCODES][DDIM] fp32, this stage
    const float* __restrict__ enormS,       // [KCODES]
    int* __restrict__ codesS,               // [M_TOTAL] this stage
    int* __restrict__ flistS, int* __restrict__ nfpS,
    int write_resid)
{
  __shared__ _Float16 Es[2][NC * 136];      // 2 x 17408 B
  __shared__ int bcode[RROWS];

  const int tid = threadIdx.x;
  const int wv = tid >> 6;
  const int l  = tid & 63;
  const int l15 = l & 15;
  const int q = l >> 4;
  const int row_base = blockIdx.x * RROWS;

  // staging indices for this thread (4 half8 per chunk, coalesced)
  const int s_code = tid >> 4;              // 0..15 (+16 per it)
  const int s_kp   = tid & 15;              // 0..15

  // ---- build f16 A-frags straight from global (once): af[rt][kc] ----
  half8 af[2][4];
  #pragma unroll
  for (int rt = 0; rt < 2; ++rt) {
    const float* pa = rin + (size_t)(row_base + wv * 32 + rt * 16 + l15) * DDIM;
    #pragma unroll
    for (int kc = 0; kc < 4; ++kc) {
      float4 x0 = *(const float4*)(pa + kc * 32 + q * 8);
      float4 x1 = *(const float4*)(pa + kc * 32 + q * 8 + 4);
      half8 h;
      h[0] = (_Float16)x0.x; h[1] = (_Float16)x0.y; h[2] = (_Float16)x0.z; h[3] = (_Float16)x0.w;
      h[4] = (_Float16)x1.x; h[5] = (_Float16)x1.y; h[6] = (_Float16)x1.z; h[7] = (_Float16)x1.w;
      af[rt][kc] = h;
    }
  }

  // ---- prologue: stage chunk 0 into Es[0] ----
  half8 pre[4];
  #pragma unroll
  for (int it = 0; it < 4; ++it) {
    int code = it * 16 + s_code;
    pre[it] = *(const half8*)(Ef16S + (size_t)code * DDIM + s_kp * 8);
  }
  #pragma unroll
  for (int it = 0; it < 4; ++it)
    *(half8*)(&Es[0][(it * 16 + s_code) * 136 + s_kp * 8]) = pre[it];
  __syncthreads();

  float v1[8], v2[8];
  int i1[8];
  #pragma unroll
  for (int s = 0; s < 8; ++s) { v1[s] = -3.0e38f; v2[s] = -3.0e38f; i1[s] = 0x7fffffff; }

  for (int cc = 0; cc < NCHUNKS; ++cc) {
    const int cur = cc & 1;

    // issue global loads for chunk cc+1 (latency hides behind this chunk's compute)
    if (cc + 1 < NCHUNKS) {
      #pragma unroll
      for (int it = 0; it < 4; ++it) {
        int code = (cc + 1) * NC + it * 16 + s_code;
        pre[it] = *(const half8*)(Ef16S + (size_t)code * DDIM + s_kp * 8);
      }
    }
    // prefetch e-norms for this chunk
    float enr[4];
    #pragma unroll
    for (int ct = 0; ct < 4; ++ct) enr[ct] = enormS[cc * NC + ct * 16 + l15];

    // compute from Es[cur]
    f32x4 acc[2][4];
    #pragma unroll
    for (int rt = 0; rt < 2; ++rt)
      #pragma unroll
      for (int ct = 0; ct < 4; ++ct) acc[rt][ct] = (f32x4){0.f, 0.f, 0.f, 0.f};

    #pragma unroll
    for (int kc = 0; kc < 4; ++kc) {
      half8 bf[4];
      #pragma unroll
      for (int ct = 0; ct < 4; ++ct)
        bf[ct] = *(const half8*)(&Es[cur][(ct * 16 + l15) * 136 + kc * 32 + q * 8]);
      #pragma unroll
      for (int rt = 0; rt < 2; ++rt)
        #pragma unroll
        for (int ct = 0; ct < 4; ++ct)
          acc[rt][ct] = __builtin_amdgcn_mfma_f32_16x16x32_f16(af[rt][kc], bf[ct], acc[rt][ct], 0, 0, 0);
    }

    // epilogue: dist = 2*dot - ||e||^2; branchless running top-2 per row-slot.
    // Codes ascend (cc, then ct) -> strict > keeps first occurrence; exact ties
    // give margin 0 <= TAU -> flagged -> exact fixup decides.
    #pragma unroll
    for (int ct = 0; ct < 4; ++ct) {
      int cgi = cc * NC + ct * 16 + l15;
      #pragma unroll
      for (int rt = 0; rt < 2; ++rt)
        #pragma unroll
        for (int reg = 0; reg < 4; ++reg) {
          float d = fmaf(2.0f, acc[rt][ct][reg], -enr[ct]);
          int s = rt * 4 + reg;
          v2[s] = fmaxf(v2[s], fminf(d, v1[s]));
          if (d > v1[s]) i1[s] = cgi;
          v1[s] = fmaxf(v1[s], d);
        }
    }

    // write prefetched chunk into the other buffer; barrier before next compute
    if (cc + 1 < NCHUNKS) {
      #pragma unroll
      for (int it = 0; it < 4; ++it)
        *(half8*)(&Es[cur ^ 1][(it * 16 + s_code) * 136 + s_kp * 8]) = pre[it];
    }
    __syncthreads();
  }

  // ---- merge top-2 across the 16 l15-lanes sharing each row (disjoint codes) ----
  #pragma unroll
  for (int s = 0; s < 8; ++s) {
    #pragma unroll
    for (int off = 1; off < 16; off <<= 1) {
      float ov1 = __shfl_xor(v1[s], off);
      int   oi1 = __shfl_xor(i1[s], off);
      float ov2 = __shfl_xor(v2[s], off);
      if (ov1 > v1[s] || (ov1 == v1[s] && oi1 < i1[s])) {
        float nv2 = fmaxf(v1[s], ov2);
        v1[s] = ov1; i1[s] = oi1; v2[s] = nv2;
      } else {
        v2[s] = fmaxf(v2[s], ov1);
      }
    }
  }
  // lane l15==0 of each q-group holds final top-2 for rows wv*32+rt*16+q*4+reg
  if (l15 == 0) {
    #pragma unroll
    for (int s = 0; s < 8; ++s) {
      int row = wv * 32 + (s >> 2) * 16 + q * 4 + (s & 3);
      bcode[row] = i1[s];
      codesS[row_base + row] = i1[s];
      if (v1[s] - v2[s] <= TAU) {
        int pos = atomicAdd(nfpS, 1);
        flistS[pos] = row_base + row;
      }
    }
  }
  __syncthreads();

  // ---- exact f32 residual update: rout = rin - embed[code] (coalesced; in-place safe) ----
  if (write_resid) {
    #pragma unroll
    for (int it = 0; it < 16; ++it) {
      int idx = it * 256 + tid;
      int r = idx >> 5, f4 = idx & 31;
      float4 e = *(const float4*)(embedS + (size_t)bcode[r] * DDIM + f4 * 4);
      float4 a = *(const float4*)(rin + (size_t)(row_base + r) * DDIM + f4 * 4);
      float4 o;
      o.x = a.x - e.x; o.y = a.y - e.y; o.z = a.z - e.z; o.w = a.w - e.w;
      *(float4*)(rout + (size_t)(row_base + r) * DDIM + f4 * 4) = o;
    }
  }
}

// ---------------- batched exact fixup (round-1-verified fp32 semantics) ----------------
__global__ __launch_bounds__(256) void rvq_fixup(
    const float* __restrict__ x,
    const float* __restrict__ embed_all, const float* __restrict__ enorm_all,
    int* __restrict__ codes, float* __restrict__ resid,
    const int* __restrict__ flistS, const int* __restrict__ nfpS,
    int stage, int write_resid)
{
  __shared__ float rowbuf[FB][DDIM];
  __shared__ float fv[256];
  __shared__ int fidx[256];
  __shared__ int rowid[FB];
  __shared__ int bestc[FB];
  const int tid = threadIdx.x;
  const int n = *nfpS;
  const float* embedS = embed_all + (size_t)stage * KCODES * DDIM;
  const float* enormS = enorm_all + (size_t)stage * KCODES;

  for (int base = blockIdx.x * FB; base < n; base += FIXGRID * FB) {
    const int nb = min(FB, n - base);
    if (tid < nb) rowid[tid] = flistS[base + tid];
    __syncthreads();

    // reconstruct exact residual: v = x - sum_{s2<stage} embed[codes[s2]] (stage order)
    for (int j0 = 0; j0 < nb; j0 += 2) {
      int j = j0 + (tid >> 7);
      int d = tid & 127;
      if (j < nb) {
        int r = rowid[j];
        float v = x[(size_t)r * DDIM + d];
        for (int s2 = 0; s2 < stage; ++s2) {
          int pc = codes[(size_t)s2 * M_TOTAL + r];
          v -= embed_all[(size_t)(s2 * KCODES + pc) * DDIM + d];
        }
        rowbuf[j][d] = v;
      }
    }
    __syncthreads();

    // exact dots: thread t -> codes {4t..4t+3} x FB rows, sequential-k fmaf chains
    float acc[4][FB];
    #pragma unroll
    for (int jc = 0; jc < 4; ++jc)
      #pragma unroll
      for (int j = 0; j < FB; ++j) acc[jc][j] = 0.f;
    for (int k4 = 0; k4 < 32; ++k4) {
      float4 rb[FB];
      #pragma unroll
      for (int j = 0; j < FB; ++j) rb[j] = *(const float4*)(&rowbuf[j][k4 * 4]);
      #pragma unroll
      for (int jc = 0; jc < 4; ++jc) {
        float4 e4 = *(const float4*)(embedS + (size_t)(tid * 4 + jc) * DDIM + k4 * 4);
        #pragma unroll
        for (int j = 0; j < FB; ++j) {
          acc[jc][j] = fmaf(rb[j].x, e4.x, acc[jc][j]);
          acc[jc][j] = fmaf(rb[j].y, e4.y, acc[jc][j]);
          acc[jc][j] = fmaf(rb[j].z, e4.z, acc[jc][j]);
          acc[jc][j] = fmaf(rb[j].w, e4.w, acc[jc][j]);
        }
      }
    }

    for (int j = 0; j < nb; ++j) {
      float bv = -3.0e38f; int bi = 0x7fffffff;
      #pragma unroll
      for (int jc = 0; jc < 4; ++jc) {
        int c = tid * 4 + jc;
        float dd = 2.0f * acc[jc][j] - enormS[c];
        if (dd > bv) { bv = dd; bi = c; }
      }
      fv[tid] = bv; fidx[tid] = bi;
      __syncthreads();
      for (int step = 128; step > 0; step >>= 1) {
        if (tid < step) {
          float o = fv[tid + step]; int oi = fidx[tid + step];
          if (o > fv[tid] || (o == fv[tid] && oi < fidx[tid])) { fv[tid] = o; fidx[tid] = oi; }
        }
        __syncthreads();
      }
      if (tid == 0) {
        bestc[j] = fidx[0];
        codes[(size_t)stage * M_TOTAL + rowid[j]] = fidx[0];
      }
      __syncthreads();
    }

    // rewrite exact f32 residual for flagged rows
    if (write_resid) {
      for (int j0 = 0; j0 < nb; j0 += 2) {
        int j = j0 + (tid >> 7);
        int d = tid & 127;
        if (j < nb) {
          int r = rowid[j];
          resid[(size_t)r * DDIM + d] = rowbuf[j][d] - embedS[(size_t)bestc[j] * DDIM + d];
        }
      }
    }
    __syncthreads();
  }
}

// ================= fallback: round-2 verified exact-fp32 kernel =================
#define F_NCHUNK  256
#define F_KC      16
#define F_AS_STRIDE 68
#define F_ES_STRIDE 260

__global__ __launch_bounds__(256, 3) void rvq_stage_kernel(
    const float* __restrict__ rin, float* __restrict__ rout,
    const float* __restrict__ embed, const float* __restrict__ enorm,
    int* __restrict__ codes)
{
  __shared__ float smem[DDIM * F_AS_STRIDE + F_KC * F_ES_STRIDE + F_NCHUNK];
  float* As  = smem;
  float* Es  = smem + DDIM * F_AS_STRIDE;
  float* Ens = Es + F_KC * F_ES_STRIDE;
  float* red_v = Es;
  int*   red_i = (int*)(Es + 64 * 33);
  int*   bcode = (int*)(Es + 2 * 64 * 33);

  const int tid = threadIdx.x;
  const int tx = tid & 31;
  const int ty = tid >> 5;
  const int row_base = blockIdx.x * 64;

  #pragma unroll
  for (int it = 0; it < 8; ++it) {
    int idx = it * 256 + tid;
    int r = idx >> 5, f4 = idx & 31;
    float4 v = *(const float4*)(rin + (size_t)(row_base + r) * DDIM + f4 * 4);
    As[(4 * f4 + 0) * F_AS_STRIDE + r] = v.x;
    As[(4 * f4 + 1) * F_AS_STRIDE + r] = v.y;
    As[(4 * f4 + 2) * F_AS_STRIDE + r] = v.z;
    As[(4 * f4 + 3) * F_AS_STRIDE + r] = v.w;
  }

  float best[8]; int bidx[8];
  #pragma unroll
  for (int i = 0; i < 8; ++i) { best[i] = -3.0e38f; bidx[i] = 0x7fffffff; }

  for (int nc = 0; nc < KCODES / F_NCHUNK; ++nc) {
    float acc[8][8];
    #pragma unroll
    for (int i = 0; i < 8; ++i)
      #pragma unroll
      for (int j = 0; j < 8; ++j) acc[i][j] = 0.0f;

    for (int kc = 0; kc < DDIM / F_KC; ++kc) {
      __syncthreads();
      #pragma unroll
      for (int it = 0; it < 4; ++it) {
        int idx = it * 256 + tid;
        int c = idx >> 2, f4 = idx & 3;
        float4 v = *(const float4*)(embed + (size_t)(nc * F_NCHUNK + c) * DDIM + kc * F_KC + f4 * 4);
        Es[(4 * f4 + 0) * F_ES_STRIDE + c] = v.x;
        Es[(4 * f4 + 1) * F_ES_STRIDE + c] = v.y;
        Es[(4 * f4 + 2) * F_ES_STRIDE + c] = v.z;
        Es[(4 * f4 + 3) * F_ES_STRIDE + c] = v.w;
      }
      if (kc == 0) Ens[tid] = enorm[nc * F_NCHUNK + tid];
      __syncthreads();

      const float* pa = As + kc * F_KC * F_AS_STRIDE + ty * 8;
      const float* pe = Es + 4 * tx;
      #pragma unroll 4
      for (int k = 0; k < F_KC; ++k) {
        float4 a0 = *(const float4*)(pa + k * F_AS_STRIDE);
        float4 a1 = *(const float4*)(pa + k * F_AS_STRIDE + 4);
        float4 e0 = *(const float4*)(pe + k * F_ES_STRIDE);
        float4 e1 = *(const float4*)(pe + k * F_ES_STRIDE + 128);
        float aa[8] = {a0.x, a0.y, a0.z, a0.w, a1.x, a1.y, a1.z, a1.w};
        float ee[8] = {e0.x, e0.y, e0.z, e0.w, e1.x, e1.y, e1.z, e1.w};
        #pragma unroll
        for (int i = 0; i < 8; ++i)
          #pragma unroll
          for (int j = 0; j < 8; ++j)
            acc[i][j] = fmaf(aa[i], ee[j], acc[i][j]);
      }
    }

    #pragma unroll
    for (int j = 0; j < 8; ++j) {
      int c_local = (j < 4) ? (4 * tx + j) : (128 + 4 * tx + (j - 4));
      float en = Ens[c_local];
      int cg = nc * F_NCHUNK + c_local;
      #pragma unroll
      for (int i = 0; i < 8; ++i) {
        float dist = 2.0f * acc[i][j] - en;
        if (dist > best[i] || (dist == best[i] && cg < bidx[i])) { best[i] = dist; bidx[i] = cg; }
      }
    }
  }

  __syncthreads();
  #pragma unroll
  for (int i = 0; i < 8; ++i) {
    red_v[(ty * 8 + i) * 33 + tx] = best[i];
    red_i[(ty * 8 + i) * 33 + tx] = bidx[i];
  }
  __syncthreads();
  if (tid < 64) {
    float bv = red_v[tid * 33]; int bi = red_i[tid * 33];
    #pragma unroll
    for (int t = 1; t < 32; ++t) {
      float v = red_v[tid * 33 + t]; int ix = red_i[tid * 33 + t];
      if (v > bv || (v == bv && ix < bi)) { bv = v; bi = ix; }
    }
    codes[row_base + tid] = bi;
    bcode[tid] = bi;
  }
  __syncthreads();
  #pragma unroll
  for (int it = 0; it < 32; ++it) {
    int idx = it * 256 + tid;
    int r = idx >> 7, d = idx & 127;
    float e = embed[(size_t)bcode[r] * DDIM + d];
    rout[(size_t)(row_base + r) * DDIM + d] = As[d * F_AS_STRIDE + r] - e;
  }
}

extern "C" void kernel_launch(void* const* d_in, const int* in_sizes, int n_in,
                              void* d_out, int out_size, void* d_ws, size_t ws_size,
                              hipStream_t stream) {
  (void)in_sizes; (void)n_in; (void)out_size;
  const float* x = (const float*)d_in[0];
  const float* embed = (const float*)d_in[1];
  int* codes = (int*)d_out;

  const size_t R_BYTES   = (size_t)M_TOTAL * DDIM * 4;            // 32 MB f32 residual
  const size_t E16_BYTES = (size_t)NQ * KCODES * DDIM * 2;        // 2 MB f16 codebook
  const size_t EN_BYTES  = (size_t)NQ * KCODES * 4;               // 32 KB
  const size_t FL_BYTES  = (size_t)NQ * M_TOTAL * 4;              // 2 MB flag lists
  const size_t need = R_BYTES + E16_BYTES + EN_BYTES + FL_BYTES + 256;

  if (ws_size >= need) {
    char* w = (char*)d_ws;
    float* resid    = (float*)w;        w += R_BYTES;
    _Float16* Ef16  = (_Float16*)w;     w += E16_BYTES;
    float* enorm    = (float*)w;        w += EN_BYTES;
    int* flist      = (int*)w;          w += FL_BYTES;
    int* nfp        = (int*)w;

    hipMemsetAsync(nfp, 0, NQ * sizeof(int), stream);
    enorm_kernel<<<dim3(NQ * KCODES / 4), dim3(256), 0, stream>>>(embed, enorm);
    esplit16_kernel<<<dim3(NQ * KCODES * DDIM / 8 / 256), dim3(256), 0, stream>>>(embed, Ef16);

    for (int q = 0; q < NQ; ++q) {
      int wr = (q < NQ - 1) ? 1 : 0;
      const float* rin = (q == 0) ? x : resid;
      rvq_screen<<<dim3(M_TOTAL / RROWS), dim3(256), 0, stream>>>(
          rin, resid,
          Ef16 + (size_t)q * KCODES * DDIM,
          embed + (size_t)q * KCODES * DDIM,
          enorm + (size_t)q * KCODES,
          codes + (size_t)q * M_TOTAL,
          flist + (size_t)q * M_TOTAL, nfp + q, wr);
      rvq_fixup<<<dim3(FIXGRID), dim3(256), 0, stream>>>(
          x, embed, enorm, codes, resid,
          flist + (size_t)q * M_TOTAL, nfp + q, q, wr);
    }
  } else {
    // fallback: verified round-2 exact-fp32 path
    const size_t resid_elems = (size_t)M_TOTAL * DDIM;
    const bool ws_ok = ws_size >= (resid_elems + (size_t)NQ * KCODES) * sizeof(float);
    float* resid = ws_ok ? (float*)d_ws : (float*)d_in[0];
    float* enorm = ws_ok ? ((float*)d_ws + resid_elems) : (float*)d_ws;

    enorm_kernel<<<dim3(NQ * KCODES / 4), dim3(256), 0, stream>>>(embed, enorm);
    for (int q = 0; q < NQ; ++q) {
      const float* rin = (q == 0) ? x : resid;
      rvq_stage_kernel<<<dim3(M_TOTAL / 64), dim3(256), 0, stream>>>(
          rin, resid, embed + (size_t)q * KCODES * DDIM,
          enorm + (size_t)q * KCODES, codes + (size_t)q * M_TOTAL);
    }
  }
}